// Round 12
// baseline (463.789 us; speedup 1.0000x reference)
//
#include <hip/hip_runtime.h>
#include <math.h>

#define L0T 365
#define L1T 366
#define LT  732
#define NTILE 46
#define NSEG 23
#define NW   4
#define NTHR 256

// sched_barrier mask: bits = instruction classes ALLOWED to cross.
// DS excluded -> cross-lane LDS exchange order pinned, all else free.
#define SB_NO_DS 0x7F

typedef short svec8 __attribute__((ext_vector_type(8)));   // 8 bf16
typedef float fvec4 __attribute__((ext_vector_type(4)));
typedef float fvec16 __attribute__((ext_vector_type(16)));
typedef unsigned uvec4 __attribute__((ext_vector_type(4)));

__device__ __forceinline__ unsigned short f2bf(float f) {
    unsigned u = __float_as_uint(f);
    u = (u + 0x7fffu + ((u >> 16) & 1u)) >> 16;
    return (unsigned short)u;
}
__device__ __forceinline__ float bf2f(unsigned short s) {
    return __uint_as_float(((unsigned)s) << 16);
}
__device__ __forceinline__ unsigned pk2(float a, float b) {
    return (unsigned)f2bf(a) | ((unsigned)f2bf(b) << 16);
}
__device__ __forceinline__ unsigned cvtpk(float a, float b) {
    unsigned r;
    asm("v_cvt_pk_bf16_f32 %0, %1, %2" : "=v"(r) : "v"(a), "v"(b));
    return r;
}
__device__ __forceinline__ float pgetv(uvec4 p, int j) {
    unsigned u = p[j >> 1];
    return bf2f((unsigned short)((j & 1) ? (u >> 16) : (u & 0xffffu)));
}
__device__ __forceinline__ svec8 pack8(float4 a, float4 c) {
    uvec4 u;
    u[0] = cvtpk(a.x, a.y); u[1] = cvtpk(a.z, a.w);
    u[2] = cvtpk(c.x, c.y); u[3] = cvtpk(c.z, c.w);
    return __builtin_bit_cast(svec8, u);
}
// posenc via HW transcendentals (input in REVOLUTIONS)
__device__ __forceinline__ void fastsc(float rev, float& s, float& c) {
    float fr;
    asm("v_fract_f32 %0, %1" : "=v"(fr) : "v"(rev));
    asm("v_sin_f32 %0, %1"   : "=v"(s)  : "v"(fr));
    asm("v_cos_f32 %0, %1"   : "=v"(c)  : "v"(fr));
}
// Opaque-pointer LDS load: LICM cannot hoist (R4 failure mode defeated).
__device__ __forceinline__ svec8 ldfrag(const unsigned short* p) {
    asm volatile("" : "+v"(p));
    return *(const svec8*)p;
}

// 2-layer embed MLP for a 16-token tile; tables in LANE ORDER
// ([2 frag][64 lane][8 bf16] -> ds_read_b128 at lane*16B, conflict-free),
// biases folded into the MFMA C operand.
__device__ __forceinline__ void embed_pass(
    const unsigned short* __restrict__ T1,
    const unsigned short* __restrict__ T2,
    const float* __restrict__ Bh, const float* __restrict__ Bx,
    svec8 bx, int ln, int Q, float* __restrict__ out)
{
    svec8 w1f0 = *(const svec8*)&T1[ln * 8];
    svec8 w1f1 = *(const svec8*)&T1[512 + ln * 8];
    const fvec4* bh = (const fvec4*)&Bh[Q * 8];
    fvec4 d0 = __builtin_amdgcn_mfma_f32_16x16x32_bf16(w1f0, bx, bh[0], 0, 0, 0);
    fvec4 d1 = __builtin_amdgcn_mfma_f32_16x16x32_bf16(w1f1, bx, bh[1], 0, 0, 0);
    uvec4 hu;
    hu[0] = cvtpk(fmaxf(d0[0], 0.f), fmaxf(d0[1], 0.f));
    hu[1] = cvtpk(fmaxf(d0[2], 0.f), fmaxf(d0[3], 0.f));
    hu[2] = cvtpk(fmaxf(d1[0], 0.f), fmaxf(d1[1], 0.f));
    hu[3] = cvtpk(fmaxf(d1[2], 0.f), fmaxf(d1[3], 0.f));
    svec8 hf = __builtin_bit_cast(svec8, hu);
    svec8 w2f0 = *(const svec8*)&T2[ln * 8];
    svec8 w2f1 = *(const svec8*)&T2[512 + ln * 8];
    const fvec4* bb = (const fvec4*)&Bx[Q * 8];
    fvec4 g0 = __builtin_amdgcn_mfma_f32_16x16x32_bf16(w2f0, hf, bb[0], 0, 0, 0);
    fvec4 g1 = __builtin_amdgcn_mfma_f32_16x16x32_bf16(w2f1, hf, bb[1], 0, 0, 0);
    out[0] = g0[0]; out[1] = g0[1]; out[2] = g0[2]; out[3] = g0[3];
    out[4] = g1[0]; out[5] = g1[1]; out[6] = g1[2]; out[7] = g1[3];
}

// Per-SEGMENT tiling: t<23 -> x0 tokens t*16+tk (<365); t>=23 -> x1 tokens
// (t-23)*16+tk (<366), slot 366 = xc token (ECV), slot 367 = zero.
__device__ __forceinline__ void load_tile(
    int t, int b, int tk, int Q,
    const float* __restrict__ x0, const float* __restrict__ x1,
    const float* __restrict__ pos0, const float* __restrict__ pos1,
    svec8& bx, float& pv, int& seg, int& tl)
{
    seg = (t >= NSEG) ? 1 : 0;
    tl  = (seg ? (t - NSEG) : t) * 16 + tk;
    const int lim = seg ? L1T : L0T;
    const bool tvalid = tl < lim;
    #pragma unroll
    for (int j = 0; j < 8; j++) bx[j] = 0;
    const bool ld = tvalid && (seg ? (Q < 2) : (Q == 0));
    if (ld) {
        const float4* px = seg
            ? (const float4*)(x1 + ((size_t)b * L1T + tl) * 16 + Q * 8)
            : (const float4*)(x0 + ((size_t)b * L0T + tl) * 8);
        bx = pack8(px[0], px[1]);
    }
    pv = 0.f;
    if (tvalid) pv = seg ? pos1[(size_t)b * L1T + tl] : pos0[(size_t)b * L0T + tl];
}

__device__ __forceinline__ void finish_xv(
    int seg, int tl, int Q, const float* __restrict__ e, float pv, float4 pwr,
    const float* __restrict__ ECV, float* __restrict__ xv)
{
    const int lim = seg ? L1T : L0T;
    const bool tvalid = tl < lim;
    const bool isxc = seg && (tl == L1T);
    const float pwa[4] = {pwr.x, pwr.y, pwr.z, pwr.w};
    #pragma unroll
    for (int j = 0; j < 8; j += 2) {
        float s, c; fastsc(pv * pwa[j >> 1], s, c);
        float a0 = e[j] + s, a1 = e[j + 1] + c;
        xv[j]     = tvalid ? a0 : (isxc ? ECV[Q * 8 + j]     : 0.f);
        xv[j + 1] = tvalid ? a1 : (isxc ? ECV[Q * 8 + j + 1] : 0.f);
    }
}

// ======================= KERNEL A: embed + Gram + attention ===============
// R12: pair-processed tiles. Both embeds of a pair share one scheduling
// region (TBL reads + MFMAs + global loads interleave); ONE pinned DS
// exchange per pair via double-slot staging (slot1 = +576 ushorts). The
// staging (9.2KB, 2x576/wave) aliases phase-2 Cm/T1f; Cm is re-zeroed
// after the loop. Single dG accumulator (2nd fvec16 would exceed the
// 64-total-reg budget -> spill, per R5).
__global__ __launch_bounds__(NTHR, 8) void embed_gram_kernel(
    const float* __restrict__ x0,  const float* __restrict__ x1,
    const float* __restrict__ pos0,const float* __restrict__ pos1,
    const float* __restrict__ xcT,
    const float* __restrict__ e0w1,const float* __restrict__ e0b1,
    const float* __restrict__ e0w2,const float* __restrict__ e0b2,
    const float* __restrict__ e1w1,const float* __restrict__ e1b1,
    const float* __restrict__ e1w2,const float* __restrict__ e1b2,
    const float* __restrict__ ecw1,const float* __restrict__ ecb1,
    const float* __restrict__ ecw2,const float* __restrict__ ecb2,
    const float* __restrict__ wq,  const float* __restrict__ wk,
    const float* __restrict__ wv,  const float* __restrict__ wo,
    unsigned short* __restrict__ wsWb, float* __restrict__ wsEC,
    uvec4* __restrict__ wsX)
{
    const int b   = blockIdx.x;
    const int tid = threadIdx.x;
    const int w   = tid >> 6;
    const int ln  = tid & 63;
    const int tk  = ln & 15;
    const int Q   = ln >> 4;

    __shared__ unsigned short TBL[4 * 1024] __attribute__((aligned(16))); // 8192 B
    __shared__ float BIA[128] __attribute__((aligned(16)));               //  512 B
    __shared__ unsigned short UNI[4608] __attribute__((aligned(16)));     // 9216 B
    __shared__ float ECV[32] __attribute__((aligned(16)));                //  128 B

    // UNI usage: phase 1 = staging [4 wave][2 slot][576]; phase 2 =
    // Cm (floats 0..1023) + T1f (floats 1152..2175).
    float* Cm  = (float*)UNI;
    float* T1f = (float*)UNI + 1152;

    float4 pwr;
    pwr.x = 0.5f / (float)(Q * 4 + 1);
    pwr.y = 0.5f / (float)(Q * 4 + 2);
    pwr.z = 0.5f / (float)(Q * 4 + 3);
    pwr.w = 0.5f / (float)(Q * 4 + 4);

    // ---- phase 0: tables + ec MLP ----
    for (int idx = tid; idx < 1024; idx += NTHR) {
        int f = idx >> 9, lane = (idx >> 3) & 63, j = idx & 7;
        int tkk = lane & 15, QQ = lane >> 4;
        int Lr = ((tkk >> 2) * 8) + (tkk & 3) + f * 4;
        int col = QQ * 8 + j;
        TBL[idx]        = (col < 8)  ? f2bf(e0w1[Lr * 8  + col]) : (unsigned short)0;
        TBL[1024 + idx] = f2bf(e0w2[Lr * 32 + col]);
        TBL[2048 + idx] = (col < 16) ? f2bf(e1w1[Lr * 16 + col]) : (unsigned short)0;
        TBL[3072 + idx] = f2bf(e1w2[Lr * 32 + col]);
    }
    if (tid < 128) {
        int s = tid >> 5, i = tid & 31;
        float bv;
        if      (s == 0) bv = e0b1[i];
        else if (s == 1) bv = e0b2[i];
        else if (s == 2) bv = e1b1[i];
        else             bv = e1b2[i];
        BIA[tid] = bv;
    }
    float* ECH = T1f;
    if (tid >= 224) {
        int i = tid - 224;
        const float4* xr = (const float4*)(xcT + (size_t)b * 32);
        const float4* wr = (const float4*)&ecw1[i * 32];
        float a = ecb1[i];
        #pragma unroll
        for (int j4 = 0; j4 < 8; j4++) {
            float4 ww = wr[j4], xx = xr[j4];
            a = fmaf(ww.x, xx.x, a); a = fmaf(ww.y, xx.y, a);
            a = fmaf(ww.z, xx.z, a); a = fmaf(ww.w, xx.w, a);
        }
        ECH[i] = fmaxf(a, 0.f);
    }
    __syncthreads();
    if (tid >= 224) {
        int i = tid - 224;
        const float4* wr = (const float4*)&ecw2[i * 32];
        float a = ecb2[i];
        #pragma unroll
        for (int j4 = 0; j4 < 8; j4++) {
            float4 ww = wr[j4];
            a = fmaf(ww.x, ECH[j4 * 4 + 0], a); a = fmaf(ww.y, ECH[j4 * 4 + 1], a);
            a = fmaf(ww.z, ECH[j4 * 4 + 2], a); a = fmaf(ww.w, ECH[j4 * 4 + 3], a);
        }
        ECV[i] = a;
        wsEC[(size_t)b * 32 + i] = a;
    }
    __syncthreads();

    // ---- phase 1: embed + Gram, PAIR-PROCESSED (+ persist X) ----
    {
        const int feat = ln & 31, half = ln >> 5;
        unsigned short* ST = UNI;
        const int wbase = w * 1152;                      // 2 slots of 576
        const int waddr = wbase + tk * 32 + (tk >> 3) * 32 + Q * 8;
        const int rbase = wbase + half * 288 + feat;
        fvec16 dG;
        #pragma unroll
        for (int i = 0; i < 16; i++) dG[i] = 0.f;
        for (int p = 0; p < 6; p++) {
            const int tA = w + 8 * p;                    // always < NTILE
            const int tB = tA + 4;
            const bool hasB = (tB < NTILE);              // wave-uniform
            svec8 bxA, bxB; float pvA = 0.f, pvB = 0.f;
            int sgA, tlA, sgB = 0, tlB = 0;
            load_tile(tA, b, tk, Q, x0, x1, pos0, pos1, bxA, pvA, sgA, tlA);
            if (hasB)
                load_tile(tB, b, tk, Q, x0, x1, pos0, pos1, bxB, pvB, sgB, tlB);
            float eA[8], eB[8];
            {
                const unsigned short* T = TBL + sgA * 2048;
                const float* Bb = BIA + sgA * 64;
                embed_pass(T, T + 1024, Bb, Bb + 32, bxA, ln, Q, eA);
            }
            if (hasB) {
                const unsigned short* T = TBL + sgB * 2048;
                const float* Bb = BIA + sgB * 64;
                embed_pass(T, T + 1024, Bb, Bb + 32, bxB, ln, Q, eB);
            }
            float xvA[8]; finish_xv(sgA, tlA, Q, eA, pvA, pwr, ECV, xvA);
            uvec4 pkA;
            pkA[0] = cvtpk(xvA[0], xvA[1]); pkA[1] = cvtpk(xvA[2], xvA[3]);
            pkA[2] = cvtpk(xvA[4], xvA[5]); pkA[3] = cvtpk(xvA[6], xvA[7]);
            if (wsX) wsX[((size_t)b * NTILE + tA) * 64 + tk * 4 + Q] = pkA;
            uvec4 pkB;
            if (hasB) {
                float xvB[8]; finish_xv(sgB, tlB, Q, eB, pvB, pwr, ECV, xvB);
                pkB[0] = cvtpk(xvB[0], xvB[1]); pkB[1] = cvtpk(xvB[2], xvB[3]);
                pkB[2] = cvtpk(xvB[4], xvB[5]); pkB[3] = cvtpk(xvB[6], xvB[7]);
                if (wsX) wsX[((size_t)b * NTILE + tB) * 64 + tk * 4 + Q] = pkB;
            }
            // ONE pinned cross-lane exchange for the pair
            __builtin_amdgcn_sched_barrier(SB_NO_DS);
            *(uvec4*)&ST[waddr] = pkA;
            if (hasB) *(uvec4*)&ST[576 + waddr] = pkB;
            __builtin_amdgcn_sched_barrier(SB_NO_DS);
            svec8 afA, afB;
            #pragma unroll
            for (int j = 0; j < 8; j++)
                afA[j] = (short)ST[rbase + j * 32];
            if (hasB) {
                #pragma unroll
                for (int j = 0; j < 8; j++)
                    afB[j] = (short)ST[576 + rbase + j * 32];
            }
            __builtin_amdgcn_sched_barrier(SB_NO_DS);
            dG = __builtin_amdgcn_mfma_f32_32x32x16_bf16(afA, afA, dG, 0, 0, 0);
            if (hasB)
                dG = __builtin_amdgcn_mfma_f32_32x32x16_bf16(afB, afB, dG, 0, 0, 0);
        }
        // staging dead; re-zero Cm (aliases staging), then accumulate
        __syncthreads();
        for (int idx = tid; idx < 1024; idx += NTHR) Cm[idx] = 0.f;
        __syncthreads();
        #pragma unroll
        for (int rg = 0; rg < 16; rg++) {
            int row = (rg & 3) + 8 * (rg >> 2) + 4 * half;
            atomicAdd(&Cm[row * 32 + feat], dG[rg]);
        }
    }
    __syncthreads();

    // ---- phase 2: attention collapse -> Wb to workspace ----
    for (int idx = tid; idx < 1024; idx += NTHR) {       // T1 = Cm * wk^T
        int i = idx >> 5, g = idx & 31;
        const float4* cr = (const float4*)&Cm[i * 32];
        const float4* wr = (const float4*)&wk[g * 32];
        float a = 0.f;
        #pragma unroll
        for (int j4 = 0; j4 < 8; j4++) {
            float4 cc = cr[j4], ww = wr[j4];
            a = fmaf(cc.x, ww.x, a); a = fmaf(cc.y, ww.y, a);
            a = fmaf(cc.z, ww.z, a); a = fmaf(cc.w, ww.w, a);
        }
        T1f[idx] = a;
    }
    __syncthreads();
    const float rsL = rsqrtf((float)LT);
    for (int idx = tid; idx < 1024; idx += NTHR) {       // T2 = wq * T1 (scaled)
        int h = idx >> 5, g = idx & 31;
        const float4* qr = (const float4*)&wq[h * 32];
        float a = 0.f;
        #pragma unroll
        for (int i4 = 0; i4 < 8; i4++) {
            float4 qq = qr[i4];
            a = fmaf(qq.x, T1f[(i4 * 4 + 0) * 32 + g], a);
            a = fmaf(qq.y, T1f[(i4 * 4 + 1) * 32 + g], a);
            a = fmaf(qq.z, T1f[(i4 * 4 + 2) * 32 + g], a);
            a = fmaf(qq.w, T1f[(i4 * 4 + 3) * 32 + g], a);
        }
        Cm[idx] = a * rsL;                               // Cm now holds T2
    }
    __syncthreads();
    {   // row softmax, 8 threads per row
        int r = tid >> 3, c0 = (tid & 7) * 4;
        float4 vv = *(const float4*)&Cm[r * 32 + c0];
        float m = fmaxf(fmaxf(vv.x, vv.y), fmaxf(vv.z, vv.w));
        m = fmaxf(m, __shfl_xor(m, 1));
        m = fmaxf(m, __shfl_xor(m, 2));
        m = fmaxf(m, __shfl_xor(m, 4));
        float ex = __expf(vv.x - m), ey = __expf(vv.y - m);
        float ez = __expf(vv.z - m), ew = __expf(vv.w - m);
        float s = ex + ey + ez + ew;
        s += __shfl_xor(s, 1); s += __shfl_xor(s, 2); s += __shfl_xor(s, 4);
        float inv = 1.f / s;
        float4 o; o.x = ex * inv; o.y = ey * inv; o.z = ez * inv; o.w = ew * inv;
        *(float4*)&Cm[r * 32 + c0] = o;
    }
    __syncthreads();
    for (int idx = tid; idx < 1024; idx += NTHR) {       // T1 = att * wv
        int h = idx >> 5, j = idx & 31;
        const float4* pr = (const float4*)&Cm[h * 32];
        float a = 0.f;
        #pragma unroll
        for (int g4 = 0; g4 < 8; g4++) {
            float4 pp = pr[g4];
            a = fmaf(pp.x, wv[(g4 * 4 + 0) * 32 + j], a);
            a = fmaf(pp.y, wv[(g4 * 4 + 1) * 32 + j], a);
            a = fmaf(pp.z, wv[(g4 * 4 + 2) * 32 + j], a);
            a = fmaf(pp.w, wv[(g4 * 4 + 3) * 32 + j], a);
        }
        T1f[idx] = a;
    }
    __syncthreads();
    for (int idx = tid; idx < 1024; idx += NTHR) {       // Wb = wo*T1 + I -> ws
        int o = idx >> 5, j = idx & 31;
        const float4* orow = (const float4*)&wo[o * 32];
        float a = 0.f;
        #pragma unroll
        for (int h4 = 0; h4 < 8; h4++) {
            float4 oo = orow[h4];
            a = fmaf(oo.x, T1f[(h4 * 4 + 0) * 32 + j], a);
            a = fmaf(oo.y, T1f[(h4 * 4 + 1) * 32 + j], a);
            a = fmaf(oo.z, T1f[(h4 * 4 + 2) * 32 + j], a);
            a = fmaf(oo.w, T1f[(h4 * 4 + 3) * 32 + j], a);
        }
        wsWb[(size_t)b * 1024 + idx] = f2bf(a + (o == j ? 1.f : 0.f));
    }
}

// Shared pipeline tail: Wb->LN1->FFN1->LN2->FFN2 for one tile from px.
__device__ __forceinline__ float pipe_tile(
    uvec4 px, const unsigned short* __restrict__ WTB, const uvec4* __restrict__ P4,
    int ln, int Q)
{
    const fvec4 zc = {0.f, 0.f, 0.f, 0.f};
    svec8 bx = __builtin_bit_cast(svec8, px);
    float xf[8];
    #pragma unroll
    for (int j = 0; j < 8; j++) xf[j] = pgetv(px, j);

    svec8 wb0 = ldfrag(&WTB[ln * 8]);
    svec8 wb1 = ldfrag(&WTB[512 + ln * 8]);
    fvec4 d0 = __builtin_amdgcn_mfma_f32_16x16x32_bf16(wb0, bx, zc, 0, 0, 0);
    fvec4 d1 = __builtin_amdgcn_mfma_f32_16x16x32_bf16(wb1, bx, zc, 0, 0, 0);
    float v[8];
    #pragma unroll
    for (int j = 0; j < 4; j++) { v[j] = d0[j]; v[4 + j] = d1[j]; }
    float S = 0.f, Sq = 0.f;
    #pragma unroll
    for (int j = 0; j < 8; j++) { S += v[j]; Sq = fmaf(v[j], v[j], Sq); }
    S  += __shfl_xor(S, 16);  Sq += __shfl_xor(Sq, 16);
    S  += __shfl_xor(S, 32);  Sq += __shfl_xor(Sq, 32);
    float mean = S * (1.f / 32.f);
    float var = fmaxf(Sq * (1.f / 32.f) - mean * mean, 0.f);
    float rs = rsqrtf(var + 1e-5f);
    uvec4 pg1 = P4[Q], pb1 = P4[4 + Q];
    float n[8];
    #pragma unroll
    for (int j = 0; j < 8; j++)
        n[j] = (v[j] - mean) * rs * pgetv(pg1, j) + pgetv(pb1, j);
    uvec4 tu;
    tu[0] = cvtpk(n[0], n[1]); tu[1] = cvtpk(n[2], n[3]);
    tu[2] = cvtpk(n[4], n[5]); tu[3] = cvtpk(n[6], n[7]);
    svec8 tf = __builtin_bit_cast(svec8, tu);
    svec8 a1f0 = ldfrag(&WTB[1024 + ln * 8]);
    svec8 a1f1 = ldfrag(&WTB[1536 + ln * 8]);
    fvec4 u0 = __builtin_amdgcn_mfma_f32_16x16x32_bf16(a1f0, tf, zc, 0, 0, 0);
    fvec4 u1 = __builtin_amdgcn_mfma_f32_16x16x32_bf16(a1f1, tf, zc, 0, 0, 0);
    uvec4 pc1 = P4[16 + Q];
    uvec4 uu;
    uu[0] = cvtpk(fmaxf(u0[0] + pgetv(pc1, 0), 0.f), fmaxf(u0[1] + pgetv(pc1, 1), 0.f));
    uu[1] = cvtpk(fmaxf(u0[2] + pgetv(pc1, 2), 0.f), fmaxf(u0[3] + pgetv(pc1, 3), 0.f));
    uu[2] = cvtpk(fmaxf(u1[0] + pgetv(pc1, 4), 0.f), fmaxf(u1[1] + pgetv(pc1, 5), 0.f));
    uu[3] = cvtpk(fmaxf(u1[2] + pgetv(pc1, 6), 0.f), fmaxf(u1[3] + pgetv(pc1, 7), 0.f));
    svec8 uf = __builtin_bit_cast(svec8, uu);
    svec8 a2f0 = ldfrag(&WTB[2048 + ln * 8]);
    svec8 a2f1 = ldfrag(&WTB[2560 + ln * 8]);
    fvec4 g0 = __builtin_amdgcn_mfma_f32_16x16x32_bf16(a2f0, uf, zc, 0, 0, 0);
    fvec4 g1 = __builtin_amdgcn_mfma_f32_16x16x32_bf16(a2f1, uf, zc, 0, 0, 0);
    uvec4 pc2 = P4[20 + Q];
    #pragma unroll
    for (int j = 0; j < 8; j++)
        v[j] = (j < 4 ? g0[j] : g1[j - 4]) + pgetv(pc2, j) + xf[j];
    float S2 = 0.f, Sq2 = 0.f;
    #pragma unroll
    for (int j = 0; j < 8; j++) { S2 += v[j]; Sq2 = fmaf(v[j], v[j], Sq2); }
    S2  += __shfl_xor(S2, 16);  Sq2 += __shfl_xor(Sq2, 16);
    S2  += __shfl_xor(S2, 32);  Sq2 += __shfl_xor(Sq2, 32);
    float mean2 = S2 * (1.f / 32.f);
    float var2 = fmaxf(Sq2 * (1.f / 32.f) - mean2 * mean2, 0.f);
    float rs2 = rsqrtf(var2 + 1e-5f);
    uvec4 pg2 = P4[8 + Q], pb2 = P4[12 + Q];
    float n2[8];
    #pragma unroll
    for (int j = 0; j < 8; j++)
        n2[j] = (v[j] - mean2) * rs2 * pgetv(pg2, j) + pgetv(pb2, j);
    uvec4 t2u;
    t2u[0] = cvtpk(n2[0], n2[1]); t2u[1] = cvtpk(n2[2], n2[3]);
    t2u[2] = cvtpk(n2[4], n2[5]); t2u[3] = cvtpk(n2[6], n2[7]);
    svec8 t2 = __builtin_bit_cast(svec8, t2u);
    svec8 a3f0 = ldfrag(&WTB[3072 + ln * 8]);
    svec8 a3f1 = ldfrag(&WTB[3584 + ln * 8]);
    fvec4 q0 = __builtin_amdgcn_mfma_f32_16x16x32_bf16(a3f0, t2, zc, 0, 0, 0);
    fvec4 q1 = __builtin_amdgcn_mfma_f32_16x16x32_bf16(a3f1, t2, zc, 0, 0, 0);
    uvec4 pc3 = P4[24 + Q], pw2 = P4[28 + Q];
    float yp = 0.f;
    #pragma unroll
    for (int j = 0; j < 8; j++) {
        float ee = (j < 4 ? q0[j] : q1[j - 4]) + pgetv(pc3, j);
        yp = fmaf(pgetv(pw2, j), fmaxf(ee, 0.f), yp);
    }
    yp += __shfl_xor(yp, 16); yp += __shfl_xor(yp, 32);
    return yp;
}

// ======================= KERNEL B-lite: pipeline from stored X ============
__global__ __launch_bounds__(NTHR, 8) void pipeline_lite_kernel(
    const float* __restrict__ ln1g,const float* __restrict__ ln1b,
    const float* __restrict__ ln2g,const float* __restrict__ ln2b,
    const float* __restrict__ f1w1,const float* __restrict__ f1b1,
    const float* __restrict__ f1w2,const float* __restrict__ f1b2,
    const float* __restrict__ f2w1,const float* __restrict__ f2b1,
    const float* __restrict__ f2w2,const float* __restrict__ f2b2,
    const unsigned short* __restrict__ wsWb, const uvec4* __restrict__ wsX,
    float* __restrict__ out)
{
    const int b   = blockIdx.x;
    const int tid = threadIdx.x;
    const int w   = tid >> 6;
    const int ln  = tid & 63;
    const int tk  = ln & 15;
    const int Q   = ln >> 4;

    __shared__ unsigned short WTB[4 * 1024] __attribute__((aligned(16))); // 8192 B
    __shared__ unsigned PCK[128] __attribute__((aligned(16)));            //  512 B
    __shared__ float red[NW * 3];

    for (int idx = tid; idx < 4096; idx += NTHR) {
        int f = idx >> 9, lane = (idx >> 3) & 63, j = idx & 7;
        int tkk = lane & 15, QQ = lane >> 4;
        int Lr = ((tkk >> 2) * 8) + (tkk & 3) + (f & 1) * 4;
        int col = QQ * 8 + j;
        int wsel = f >> 1;
        unsigned short vbf;
        if      (wsel == 0) vbf = wsWb[(size_t)b * 1024 + Lr * 32 + col];
        else if (wsel == 1) vbf = f2bf(f1w1[Lr * 32 + col]);
        else if (wsel == 2) vbf = f2bf(f1w2[Lr * 32 + col]);
        else                vbf = f2bf(f2w1[Lr * 32 + col]);
        WTB[idx] = vbf;
    }
    if (tid < 128) {
        int t8 = tid >> 4, q = (tid >> 2) & 3, i = tid & 3, f = q * 8 + 2 * i;
        const float* sp;
        if      (t8 == 0) sp = ln1g;
        else if (t8 == 1) sp = ln1b;
        else if (t8 == 2) sp = ln2g;
        else if (t8 == 3) sp = ln2b;
        else if (t8 == 4) sp = f1b1;
        else if (t8 == 5) sp = f1b2;
        else if (t8 == 6) sp = f2b1;
        else              sp = f2w2;
        PCK[tid] = pk2(sp[f], sp[f + 1]);
    }
    __syncthreads();

    const float ybias = f2b2[0];
    const uvec4* P4 = (const uvec4*)PCK;

    float s0 = 0.f, s1 = 0.f, s2 = 0.f;
    for (int t = w; t < NTILE; t += NW) {
        uvec4 px = wsX[((size_t)b * NTILE + t) * 64 + tk * 4 + Q];
        float yp = pipe_tile(px, WTB, P4, ln, Q);
        if (Q == 0) {
            const int sg = (t >= NSEG) ? 1 : 0;
            const int tl = (sg ? (t - NSEG) : t) * 16 + tk;
            float yv = yp + ybias;
            if (sg == 0) { if (tl < L0T) s0 += yv; }
            else {
                if (tl < L1T)       s1 += yv;
                else if (tl == L1T) s2 += yv;
            }
        }
    }

    s0 += __shfl_xor(s0, 1); s0 += __shfl_xor(s0, 2);
    s0 += __shfl_xor(s0, 4); s0 += __shfl_xor(s0, 8);
    s1 += __shfl_xor(s1, 1); s1 += __shfl_xor(s1, 2);
    s1 += __shfl_xor(s1, 4); s1 += __shfl_xor(s1, 8);
    s2 += __shfl_xor(s2, 1); s2 += __shfl_xor(s2, 2);
    s2 += __shfl_xor(s2, 4); s2 += __shfl_xor(s2, 8);
    if (ln == 0) { red[w * 3] = s0; red[w * 3 + 1] = s1; red[w * 3 + 2] = s2; }
    __syncthreads();
    if (tid == 0) {
        float a0 = 0.f, a1 = 0.f, a2 = 0.f;
        #pragma unroll
        for (int k = 0; k < NW; k++) {
            a0 += red[k * 3]; a1 += red[k * 3 + 1]; a2 += red[k * 3 + 2];
        }
        out[b] = a0 / (float)L0T + a1 / (float)L1T + a2;
    }
}

// ======================= KERNEL B-full: fallback (recompute embed) ========
__global__ __launch_bounds__(NTHR, 8) void pipeline_full_kernel(
    const float* __restrict__ x0,  const float* __restrict__ x1,
    const float* __restrict__ pos0,const float* __restrict__ pos1,
    const float* __restrict__ e0w1,const float* __restrict__ e0b1,
    const float* __restrict__ e0w2,const float* __restrict__ e0b2,
    const float* __restrict__ e1w1,const float* __restrict__ e1b1,
    const float* __restrict__ e1w2,const float* __restrict__ e1b2,
    const float* __restrict__ ln1g,const float* __restrict__ ln1b,
    const float* __restrict__ ln2g,const float* __restrict__ ln2b,
    const float* __restrict__ f1w1,const float* __restrict__ f1b1,
    const float* __restrict__ f1w2,const float* __restrict__ f1b2,
    const float* __restrict__ f2w1,const float* __restrict__ f2b1,
    const float* __restrict__ f2w2,const float* __restrict__ f2b2,
    const unsigned short* __restrict__ wsWb, const float* __restrict__ wsEC,
    float* __restrict__ out)
{
    const int b   = blockIdx.x;
    const int tid = threadIdx.x;
    const int w   = tid >> 6;
    const int ln  = tid & 63;
    const int tk  = ln & 15;
    const int Q   = ln >> 4;

    __shared__ unsigned short TBL[4 * 1024] __attribute__((aligned(16)));
    __shared__ unsigned short WTB[4 * 1024] __attribute__((aligned(16)));
    __shared__ float BIA[128] __attribute__((aligned(16)));
    __shared__ unsigned PCK[128] __attribute__((aligned(16)));
    __shared__ float ECV[32] __attribute__((aligned(16)));
    __shared__ float red[NW * 3];

    float4 pwr;
    pwr.x = 0.5f / (float)(Q * 4 + 1);
    pwr.y = 0.5f / (float)(Q * 4 + 2);
    pwr.z = 0.5f / (float)(Q * 4 + 3);
    pwr.w = 0.5f / (float)(Q * 4 + 4);

    for (int idx = tid; idx < 1024; idx += NTHR) {
        int f = idx >> 9, lane = (idx >> 3) & 63, j = idx & 7;
        int tkk = lane & 15, QQ = lane >> 4;
        int Lr = ((tkk >> 2) * 8) + (tkk & 3) + f * 4;
        int col = QQ * 8 + j;
        TBL[idx]        = (col < 8)  ? f2bf(e0w1[Lr * 8  + col]) : (unsigned short)0;
        TBL[1024 + idx] = f2bf(e0w2[Lr * 32 + col]);
        TBL[2048 + idx] = (col < 16) ? f2bf(e1w1[Lr * 16 + col]) : (unsigned short)0;
        TBL[3072 + idx] = f2bf(e1w2[Lr * 32 + col]);
    }
    for (int idx = tid; idx < 4096; idx += NTHR) {
        int f = idx >> 9, lane = (idx >> 3) & 63, j = idx & 7;
        int tkk = lane & 15, QQ = lane >> 4;
        int Lr = ((tkk >> 2) * 8) + (tkk & 3) + (f & 1) * 4;
        int col = QQ * 8 + j;
        int wsel = f >> 1;
        unsigned short vbf;
        if      (wsel == 0) vbf = wsWb[(size_t)b * 1024 + Lr * 32 + col];
        else if (wsel == 1) vbf = f2bf(f1w1[Lr * 32 + col]);
        else if (wsel == 2) vbf = f2bf(f1w2[Lr * 32 + col]);
        else                vbf = f2bf(f2w1[Lr * 32 + col]);
        WTB[idx] = vbf;
    }
    if (tid < 128) {
        int s = tid >> 5, i = tid & 31;
        float bv;
        if      (s == 0) bv = e0b1[i];
        else if (s == 1) bv = e0b2[i];
        else if (s == 2) bv = e1b1[i];
        else             bv = e1b2[i];
        BIA[tid] = bv;
    }
    if (tid < 128) {
        int t8 = tid >> 4, q = (tid >> 2) & 3, i = tid & 3, f = q * 8 + 2 * i;
        const float* sp;
        if      (t8 == 0) sp = ln1g;
        else if (t8 == 1) sp = ln1b;
        else if (t8 == 2) sp = ln2g;
        else if (t8 == 3) sp = ln2b;
        else if (t8 == 4) sp = f1b1;
        else if (t8 == 5) sp = f1b2;
        else if (t8 == 6) sp = f2b1;
        else              sp = f2w2;
        PCK[tid] = pk2(sp[f], sp[f + 1]);
    }
    if (tid < 32) ECV[tid] = wsEC[(size_t)b * 32 + tid];
    __syncthreads();

    const float ybias = f2b2[0];
    const uvec4* P4 = (const uvec4*)PCK;

    float s0 = 0.f, s1 = 0.f, s2 = 0.f;
    for (int t = w; t < NTILE; t += NW) {
        svec8 bx0; float pv; int sg, tl;
        load_tile(t, b, tk, Q, x0, x1, pos0, pos1, bx0, pv, sg, tl);
        float e[8];
        {
            const unsigned short* T = TBL + sg * 2048;
            const float* Bb = BIA + sg * 64;
            embed_pass(T, T + 1024, Bb, Bb + 32, bx0, ln, Q, e);
        }
        float xv[8]; finish_xv(sg, tl, Q, e, pv, pwr, ECV, xv);
        uvec4 pkx;
        pkx[0] = cvtpk(xv[0], xv[1]); pkx[1] = cvtpk(xv[2], xv[3]);
        pkx[2] = cvtpk(xv[4], xv[5]); pkx[3] = cvtpk(xv[6], xv[7]);
        float yp = pipe_tile(pkx, WTB, P4, ln, Q);
        if (Q == 0) {
            float yv = yp + ybias;
            if (sg == 0) { if (tl < L0T) s0 += yv; }
            else {
                if (tl < L1T)       s1 += yv;
                else if (tl == L1T) s2 += yv;
            }
        }
    }

    s0 += __shfl_xor(s0, 1); s0 += __shfl_xor(s0, 2);
    s0 += __shfl_xor(s0, 4); s0 += __shfl_xor(s0, 8);
    s1 += __shfl_xor(s1, 1); s1 += __shfl_xor(s1, 2);
    s1 += __shfl_xor(s1, 4); s1 += __shfl_xor(s1, 8);
    s2 += __shfl_xor(s2, 1); s2 += __shfl_xor(s2, 2);
    s2 += __shfl_xor(s2, 4); s2 += __shfl_xor(s2, 8);
    if (ln == 0) { red[w * 3] = s0; red[w * 3 + 1] = s1; red[w * 3 + 2] = s2; }
    __syncthreads();
    if (tid == 0) {
        float a0 = 0.f, a1 = 0.f, a2 = 0.f;
        #pragma unroll
        for (int k = 0; k < NW; k++) {
            a0 += red[k * 3]; a1 += red[k * 3 + 1]; a2 += red[k * 3 + 2];
        }
        out[b] = a0 / (float)L0T + a1 / (float)L1T + a2;
    }
}

extern "C" void kernel_launch(void* const* d_in, const int* in_sizes, int n_in,
                              void* d_out, int out_size, void* d_ws, size_t ws_size,
                              hipStream_t stream)
{
    const float* x0   = (const float*)d_in[0];
    const float* x1   = (const float*)d_in[1];
    const float* pos0 = (const float*)d_in[2];
    const float* pos1 = (const float*)d_in[3];
    const float* xcT  = (const float*)d_in[4];
    const float* e0w1 = (const float*)d_in[5];
    const float* e0b1 = (const float*)d_in[6];
    const float* e0w2 = (const float*)d_in[7];
    const float* e0b2 = (const float*)d_in[8];
    const float* e1w1 = (const float*)d_in[9];
    const float* e1b1 = (const float*)d_in[10];
    const float* e1w2 = (const float*)d_in[11];
    const float* e1b2 = (const float*)d_in[12];
    const float* ecw1 = (const float*)d_in[13];
    const float* ecb1 = (const float*)d_in[14];
    const float* ecw2 = (const float*)d_in[15];
    const float* ecb2 = (const float*)d_in[16];
    const float* wq   = (const float*)d_in[17];
    const float* wk   = (const float*)d_in[18];
    const float* wv   = (const float*)d_in[19];
    const float* wo   = (const float*)d_in[20];
    const float* ln1g = (const float*)d_in[21];
    const float* ln1b = (const float*)d_in[22];
    const float* ln2g = (const float*)d_in[23];
    const float* ln2b = (const float*)d_in[24];
    const float* f1w1 = (const float*)d_in[25];
    const float* f1b1 = (const float*)d_in[26];
    const float* f1w2 = (const float*)d_in[27];
    const float* f1b2 = (const float*)d_in[28];
    const float* f2w1 = (const float*)d_in[29];
    const float* f2b1 = (const float*)d_in[30];
    const float* f2w2 = (const float*)d_in[31];
    const float* f2b2 = (const float*)d_in[32];
    float* out = (float*)d_out;

    const int B = in_sizes[0] / (L0T * 8);

    unsigned short* wsWb = (unsigned short*)d_ws;                  // B*1024 bf16
    float* wsEC = (float*)((char*)d_ws + (size_t)B * 1024 * 2);    // B*32 f32
    size_t offX = (size_t)B * 1024 * 2 + (size_t)B * 32 * 4;
    size_t needX = offX + (size_t)B * NTILE * 64 * 16;             // B*46*64 uvec4
    const bool lite = (ws_size >= needX);
    uvec4* wsX = lite ? (uvec4*)((char*)d_ws + offX) : (uvec4*)nullptr;

    hipLaunchKernelGGL(embed_gram_kernel, dim3(B), dim3(NTHR), 0, stream,
                       x0, x1, pos0, pos1, xcT,
                       e0w1, e0b1, e0w2, e0b2, e1w1, e1b1, e1w2, e1b2,
                       ecw1, ecb1, ecw2, ecb2, wq, wk, wv, wo,
                       wsWb, wsEC, wsX);
    if (lite) {
        hipLaunchKernelGGL(pipeline_lite_kernel, dim3(B), dim3(NTHR), 0, stream,
                           ln1g, ln1b, ln2g, ln2b,
                           f1w1, f1b1, f1w2, f1b2, f2w1, f2b1, f2w2, f2b2,
                           wsWb, wsX, out);
    } else {
        hipLaunchKernelGGL(pipeline_full_kernel, dim3(B), dim3(NTHR), 0, stream,
                           x0, x1, pos0, pos1,
                           e0w1, e0b1, e0w2, e0b2, e1w1, e1b1, e1w2, e1b2,
                           ln1g, ln1b, ln2g, ln2b,
                           f1w1, f1b1, f1w2, f1b2, f2w1, f2b1, f2w2, f2b2,
                           wsWb, wsEC, out);
    }
}

// Round 13
// 311.904 us; speedup vs baseline: 1.4870x; 1.4870x over previous
//
#include <hip/hip_runtime.h>
#include <math.h>

#define L0T 365
#define L1T 366
#define LT  732
#define NTILE 46
#define NSEG 23
#define NW   4
#define NTHR 256

// sched_barrier mask: bits = instruction classes ALLOWED to cross.
// DS excluded -> cross-lane LDS exchange order pinned, all else free.
#define SB_NO_DS 0x7F

typedef short svec8 __attribute__((ext_vector_type(8)));   // 8 bf16
typedef float fvec4 __attribute__((ext_vector_type(4)));
typedef float fvec16 __attribute__((ext_vector_type(16)));
typedef unsigned uvec4 __attribute__((ext_vector_type(4)));

__device__ __forceinline__ unsigned short f2bf(float f) {
    unsigned u = __float_as_uint(f);
    u = (u + 0x7fffu + ((u >> 16) & 1u)) >> 16;
    return (unsigned short)u;
}
__device__ __forceinline__ float bf2f(unsigned short s) {
    return __uint_as_float(((unsigned)s) << 16);
}
__device__ __forceinline__ unsigned pk2(float a, float b) {
    return (unsigned)f2bf(a) | ((unsigned)f2bf(b) << 16);
}
__device__ __forceinline__ unsigned cvtpk(float a, float b) {
    unsigned r;
    asm("v_cvt_pk_bf16_f32 %0, %1, %2" : "=v"(r) : "v"(a), "v"(b));
    return r;
}
__device__ __forceinline__ float pgetv(uvec4 p, int j) {
    unsigned u = p[j >> 1];
    return bf2f((unsigned short)((j & 1) ? (u >> 16) : (u & 0xffffu)));
}
__device__ __forceinline__ svec8 pack8(float4 a, float4 c) {
    uvec4 u;
    u[0] = cvtpk(a.x, a.y); u[1] = cvtpk(a.z, a.w);
    u[2] = cvtpk(c.x, c.y); u[3] = cvtpk(c.z, c.w);
    return __builtin_bit_cast(svec8, u);
}
// posenc via HW transcendentals (input in REVOLUTIONS)
__device__ __forceinline__ void fastsc(float rev, float& s, float& c) {
    float fr;
    asm("v_fract_f32 %0, %1" : "=v"(fr) : "v"(rev));
    asm("v_sin_f32 %0, %1"   : "=v"(s)  : "v"(fr));
    asm("v_cos_f32 %0, %1"   : "=v"(c)  : "v"(fr));
}
// Opaque-pointer LDS load: LICM cannot hoist (R4 failure mode defeated).
__device__ __forceinline__ svec8 ldfrag(const unsigned short* p) {
    asm volatile("" : "+v"(p));
    return *(const svec8*)p;
}

// 2-layer embed MLP for a 16-token tile; tables in LANE ORDER
// ([2 frag][64 lane][8 bf16] -> ds_read_b128 at lane*16B, conflict-free),
// biases folded into the MFMA C operand.
__device__ __forceinline__ void embed_pass(
    const unsigned short* __restrict__ T1,
    const unsigned short* __restrict__ T2,
    const float* __restrict__ Bh, const float* __restrict__ Bx,
    svec8 bx, int ln, int Q, float* __restrict__ out)
{
    svec8 w1f0 = *(const svec8*)&T1[ln * 8];
    svec8 w1f1 = *(const svec8*)&T1[512 + ln * 8];
    const fvec4* bh = (const fvec4*)&Bh[Q * 8];
    fvec4 d0 = __builtin_amdgcn_mfma_f32_16x16x32_bf16(w1f0, bx, bh[0], 0, 0, 0);
    fvec4 d1 = __builtin_amdgcn_mfma_f32_16x16x32_bf16(w1f1, bx, bh[1], 0, 0, 0);
    uvec4 hu;
    hu[0] = cvtpk(fmaxf(d0[0], 0.f), fmaxf(d0[1], 0.f));
    hu[1] = cvtpk(fmaxf(d0[2], 0.f), fmaxf(d0[3], 0.f));
    hu[2] = cvtpk(fmaxf(d1[0], 0.f), fmaxf(d1[1], 0.f));
    hu[3] = cvtpk(fmaxf(d1[2], 0.f), fmaxf(d1[3], 0.f));
    svec8 hf = __builtin_bit_cast(svec8, hu);
    svec8 w2f0 = *(const svec8*)&T2[ln * 8];
    svec8 w2f1 = *(const svec8*)&T2[512 + ln * 8];
    const fvec4* bb = (const fvec4*)&Bx[Q * 8];
    fvec4 g0 = __builtin_amdgcn_mfma_f32_16x16x32_bf16(w2f0, hf, bb[0], 0, 0, 0);
    fvec4 g1 = __builtin_amdgcn_mfma_f32_16x16x32_bf16(w2f1, hf, bb[1], 0, 0, 0);
    out[0] = g0[0]; out[1] = g0[1]; out[2] = g0[2]; out[3] = g0[3];
    out[4] = g1[0]; out[5] = g1[1]; out[6] = g1[2]; out[7] = g1[3];
}

// Per-SEGMENT tiling: t<23 -> x0 tokens t*16+tk (<365); t>=23 -> x1 tokens
// (t-23)*16+tk (<366), slot 366 = xc token (ECV), slot 367 = zero.
// RAW variant: returns the unpacked float4 pair + pos (for prefetching);
// pack happens at consumption time.
__device__ __forceinline__ void load_raw(
    int t, int b, int tk, int Q,
    const float* __restrict__ x0, const float* __restrict__ x1,
    const float* __restrict__ pos0, const float* __restrict__ pos1,
    float4& ra, float4& rc, float& pv, int& seg, int& tl)
{
    seg = (t >= NSEG) ? 1 : 0;
    tl  = (seg ? (t - NSEG) : t) * 16 + tk;
    const int lim = seg ? L1T : L0T;
    const bool tvalid = tl < lim;
    ra = make_float4(0.f, 0.f, 0.f, 0.f);
    rc = ra;
    const bool ld = tvalid && (seg ? (Q < 2) : (Q == 0));
    if (ld) {
        const float4* px = seg
            ? (const float4*)(x1 + ((size_t)b * L1T + tl) * 16 + Q * 8)
            : (const float4*)(x0 + ((size_t)b * L0T + tl) * 8);
        ra = px[0]; rc = px[1];
    }
    pv = 0.f;
    if (tvalid) pv = seg ? pos1[(size_t)b * L1T + tl] : pos0[(size_t)b * L0T + tl];
}
// Packed-load variant (used by B-full fallback).
__device__ __forceinline__ void load_tile(
    int t, int b, int tk, int Q,
    const float* __restrict__ x0, const float* __restrict__ x1,
    const float* __restrict__ pos0, const float* __restrict__ pos1,
    svec8& bx, float& pv, int& seg, int& tl)
{
    float4 ra, rc;
    load_raw(t, b, tk, Q, x0, x1, pos0, pos1, ra, rc, pv, seg, tl);
    bx = pack8(ra, rc);
}

__device__ __forceinline__ void finish_xv(
    int seg, int tl, int Q, const float* __restrict__ e, float pv, float4 pwr,
    const float* __restrict__ ECV, float* __restrict__ xv)
{
    const int lim = seg ? L1T : L0T;
    const bool tvalid = tl < lim;
    const bool isxc = seg && (tl == L1T);
    const float pwa[4] = {pwr.x, pwr.y, pwr.z, pwr.w};
    #pragma unroll
    for (int j = 0; j < 8; j += 2) {
        float s, c; fastsc(pv * pwa[j >> 1], s, c);
        float a0 = e[j] + s, a1 = e[j + 1] + c;
        xv[j]     = tvalid ? a0 : (isxc ? ECV[Q * 8 + j]     : 0.f);
        xv[j + 1] = tvalid ? a1 : (isxc ? ECV[Q * 8 + j + 1] : 0.f);
    }
}

// ======================= KERNEL A: embed + Gram + attention ===============
// R13 = R11 (the proven 100us version) + MINIMAL-STATE prefetch: only the
// next tile's raw inputs (2x float4 + pos = 9 regs) are loaded one
// iteration ahead, so the current tile's embed+exchange covers the global
// load latency. NO pair duplication (R5/R8/R12 all spilled doing that).
__global__ __launch_bounds__(NTHR, 8) void embed_gram_kernel(
    const float* __restrict__ x0,  const float* __restrict__ x1,
    const float* __restrict__ pos0,const float* __restrict__ pos1,
    const float* __restrict__ xcT,
    const float* __restrict__ e0w1,const float* __restrict__ e0b1,
    const float* __restrict__ e0w2,const float* __restrict__ e0b2,
    const float* __restrict__ e1w1,const float* __restrict__ e1b1,
    const float* __restrict__ e1w2,const float* __restrict__ e1b2,
    const float* __restrict__ ecw1,const float* __restrict__ ecb1,
    const float* __restrict__ ecw2,const float* __restrict__ ecb2,
    const float* __restrict__ wq,  const float* __restrict__ wk,
    const float* __restrict__ wv,  const float* __restrict__ wo,
    unsigned short* __restrict__ wsWb, float* __restrict__ wsEC,
    uvec4* __restrict__ wsX)
{
    const int b   = blockIdx.x;
    const int tid = threadIdx.x;
    const int w   = tid >> 6;
    const int ln  = tid & 63;
    const int tk  = ln & 15;
    const int Q   = ln >> 4;

    __shared__ unsigned short TBL[4 * 1024] __attribute__((aligned(16))); // 8192 B
    __shared__ float BIA[128] __attribute__((aligned(16)));               //  512 B
    __shared__ unsigned short SCB[2304] __attribute__((aligned(16)));     // 4608 B (STG | T1f)
    __shared__ float Cm[1024] __attribute__((aligned(16)));               // 4096 B
    __shared__ float ECV[32] __attribute__((aligned(16)));                //  128 B

    float* T1f = (float*)SCB;          // phase-2 scratch (aliases staging)

    float4 pwr;
    pwr.x = 0.5f / (float)(Q * 4 + 1);
    pwr.y = 0.5f / (float)(Q * 4 + 2);
    pwr.z = 0.5f / (float)(Q * 4 + 3);
    pwr.w = 0.5f / (float)(Q * 4 + 4);

    // ---- phase 0: tables + ec MLP ----
    for (int idx = tid; idx < 1024; idx += NTHR) {
        int f = idx >> 9, lane = (idx >> 3) & 63, j = idx & 7;
        int tkk = lane & 15, QQ = lane >> 4;
        int Lr = ((tkk >> 2) * 8) + (tkk & 3) + f * 4;
        int col = QQ * 8 + j;
        TBL[idx]        = (col < 8)  ? f2bf(e0w1[Lr * 8  + col]) : (unsigned short)0;
        TBL[1024 + idx] = f2bf(e0w2[Lr * 32 + col]);
        TBL[2048 + idx] = (col < 16) ? f2bf(e1w1[Lr * 16 + col]) : (unsigned short)0;
        TBL[3072 + idx] = f2bf(e1w2[Lr * 32 + col]);
        Cm[idx] = 0.f;
    }
    if (tid < 128) {
        int s = tid >> 5, i = tid & 31;
        float bv;
        if      (s == 0) bv = e0b1[i];
        else if (s == 1) bv = e0b2[i];
        else if (s == 2) bv = e1b1[i];
        else             bv = e1b2[i];
        BIA[tid] = bv;
    }
    float* ECH = T1f;
    if (tid >= 224) {
        int i = tid - 224;
        const float4* xr = (const float4*)(xcT + (size_t)b * 32);
        const float4* wr = (const float4*)&ecw1[i * 32];
        float a = ecb1[i];
        #pragma unroll
        for (int j4 = 0; j4 < 8; j4++) {
            float4 ww = wr[j4], xx = xr[j4];
            a = fmaf(ww.x, xx.x, a); a = fmaf(ww.y, xx.y, a);
            a = fmaf(ww.z, xx.z, a); a = fmaf(ww.w, xx.w, a);
        }
        ECH[i] = fmaxf(a, 0.f);
    }
    __syncthreads();
    if (tid >= 224) {
        int i = tid - 224;
        const float4* wr = (const float4*)&ecw2[i * 32];
        float a = ecb2[i];
        #pragma unroll
        for (int j4 = 0; j4 < 8; j4++) {
            float4 ww = wr[j4];
            a = fmaf(ww.x, ECH[j4 * 4 + 0], a); a = fmaf(ww.y, ECH[j4 * 4 + 1], a);
            a = fmaf(ww.z, ECH[j4 * 4 + 2], a); a = fmaf(ww.w, ECH[j4 * 4 + 3], a);
        }
        ECV[i] = a;
        wsEC[(size_t)b * 32 + i] = a;
    }
    __syncthreads();

    // ---- phase 1: embed + Gram (+ persist X), load-only prefetch ----
    {
        const int feat = ln & 31, half = ln >> 5;
        const int wbase = w * 576;
        const int waddr = wbase + tk * 32 + (tk >> 3) * 32 + Q * 8;
        const int rbase = wbase + half * 288 + feat;
        fvec16 dG;
        #pragma unroll
        for (int i = 0; i < 16; i++) dG[i] = 0.f;

        float4 raN, rcN; float pvN; int sgN, tlN;
        load_raw(w, b, tk, Q, x0, x1, pos0, pos1, raN, rcN, pvN, sgN, tlN);
        for (int t = w; t < NTILE; t += NW) {
            // consume prefetched inputs for tile t
            svec8 bx = pack8(raN, rcN);
            const float pv = pvN;
            const int sg = sgN, tl = tlN;
            // issue next tile's loads NOW (covered by embed+exchange below)
            const int tn = t + NW;
            if (tn < NTILE)
                load_raw(tn, b, tk, Q, x0, x1, pos0, pos1, raN, rcN, pvN, sgN, tlN);

            float e[8];
            {
                const unsigned short* T = TBL + sg * 2048;
                const float* Bb = BIA + sg * 64;
                embed_pass(T, T + 1024, Bb, Bb + 32, bx, ln, Q, e);
            }
            float xv[8]; finish_xv(sg, tl, Q, e, pv, pwr, ECV, xv);
            uvec4 pk;
            pk[0] = cvtpk(xv[0], xv[1]); pk[1] = cvtpk(xv[2], xv[3]);
            pk[2] = cvtpk(xv[4], xv[5]); pk[3] = cvtpk(xv[6], xv[7]);
            if (wsX)   // persist X for kernel B (coalesced 1KB/tile/wave)
                wsX[((size_t)b * NTILE + t) * 64 + tk * 4 + Q] = pk;
            // cross-lane LDS exchange: DS order pinned, all else may cross
            __builtin_amdgcn_sched_barrier(SB_NO_DS);
            *(uvec4*)&SCB[waddr] = pk;
            __builtin_amdgcn_sched_barrier(SB_NO_DS);
            svec8 af;
            #pragma unroll
            for (int j = 0; j < 8; j++)
                af[j] = (short)SCB[rbase + j * 32];
            __builtin_amdgcn_sched_barrier(SB_NO_DS);
            dG = __builtin_amdgcn_mfma_f32_32x32x16_bf16(af, af, dG, 0, 0, 0);
        }
        #pragma unroll
        for (int rg = 0; rg < 16; rg++) {
            int row = (rg & 3) + 8 * (rg >> 2) + 4 * half;
            atomicAdd(&Cm[row * 32 + feat], dG[rg]);
        }
    }
    __syncthreads();

    // ---- phase 2: attention collapse -> Wb to workspace ----
    for (int idx = tid; idx < 1024; idx += NTHR) {       // T1 = Cm * wk^T
        int i = idx >> 5, g = idx & 31;
        const float4* cr = (const float4*)&Cm[i * 32];
        const float4* wr = (const float4*)&wk[g * 32];
        float a = 0.f;
        #pragma unroll
        for (int j4 = 0; j4 < 8; j4++) {
            float4 cc = cr[j4], ww = wr[j4];
            a = fmaf(cc.x, ww.x, a); a = fmaf(cc.y, ww.y, a);
            a = fmaf(cc.z, ww.z, a); a = fmaf(cc.w, ww.w, a);
        }
        T1f[idx] = a;
    }
    __syncthreads();
    const float rsL = rsqrtf((float)LT);
    for (int idx = tid; idx < 1024; idx += NTHR) {       // T2 = wq * T1 (scaled)
        int h = idx >> 5, g = idx & 31;
        const float4* qr = (const float4*)&wq[h * 32];
        float a = 0.f;
        #pragma unroll
        for (int i4 = 0; i4 < 8; i4++) {
            float4 qq = qr[i4];
            a = fmaf(qq.x, T1f[(i4 * 4 + 0) * 32 + g], a);
            a = fmaf(qq.y, T1f[(i4 * 4 + 1) * 32 + g], a);
            a = fmaf(qq.z, T1f[(i4 * 4 + 2) * 32 + g], a);
            a = fmaf(qq.w, T1f[(i4 * 4 + 3) * 32 + g], a);
        }
        Cm[idx] = a * rsL;                               // Cm now holds T2
    }
    __syncthreads();
    {   // row softmax, 8 threads per row
        int r = tid >> 3, c0 = (tid & 7) * 4;
        float4 vv = *(const float4*)&Cm[r * 32 + c0];
        float m = fmaxf(fmaxf(vv.x, vv.y), fmaxf(vv.z, vv.w));
        m = fmaxf(m, __shfl_xor(m, 1));
        m = fmaxf(m, __shfl_xor(m, 2));
        m = fmaxf(m, __shfl_xor(m, 4));
        float ex = __expf(vv.x - m), ey = __expf(vv.y - m);
        float ez = __expf(vv.z - m), ew = __expf(vv.w - m);
        float s = ex + ey + ez + ew;
        s += __shfl_xor(s, 1); s += __shfl_xor(s, 2); s += __shfl_xor(s, 4);
        float inv = 1.f / s;
        float4 o; o.x = ex * inv; o.y = ey * inv; o.z = ez * inv; o.w = ew * inv;
        *(float4*)&Cm[r * 32 + c0] = o;
    }
    __syncthreads();
    for (int idx = tid; idx < 1024; idx += NTHR) {       // T1 = att * wv
        int h = idx >> 5, j = idx & 31;
        const float4* pr = (const float4*)&Cm[h * 32];
        float a = 0.f;
        #pragma unroll
        for (int g4 = 0; g4 < 8; g4++) {
            float4 pp = pr[g4];
            a = fmaf(pp.x, wv[(g4 * 4 + 0) * 32 + j], a);
            a = fmaf(pp.y, wv[(g4 * 4 + 1) * 32 + j], a);
            a = fmaf(pp.z, wv[(g4 * 4 + 2) * 32 + j], a);
            a = fmaf(pp.w, wv[(g4 * 4 + 3) * 32 + j], a);
        }
        T1f[idx] = a;
    }
    __syncthreads();
    for (int idx = tid; idx < 1024; idx += NTHR) {       // Wb = wo*T1 + I -> ws
        int o = idx >> 5, j = idx & 31;
        const float4* orow = (const float4*)&wo[o * 32];
        float a = 0.f;
        #pragma unroll
        for (int h4 = 0; h4 < 8; h4++) {
            float4 oo = orow[h4];
            a = fmaf(oo.x, T1f[(h4 * 4 + 0) * 32 + j], a);
            a = fmaf(oo.y, T1f[(h4 * 4 + 1) * 32 + j], a);
            a = fmaf(oo.z, T1f[(h4 * 4 + 2) * 32 + j], a);
            a = fmaf(oo.w, T1f[(h4 * 4 + 3) * 32 + j], a);
        }
        wsWb[(size_t)b * 1024 + idx] = f2bf(a + (o == j ? 1.f : 0.f));
    }
}

// Shared pipeline tail: Wb->LN1->FFN1->LN2->FFN2 for one tile from px.
__device__ __forceinline__ float pipe_tile(
    uvec4 px, const unsigned short* __restrict__ WTB, const uvec4* __restrict__ P4,
    int ln, int Q)
{
    const fvec4 zc = {0.f, 0.f, 0.f, 0.f};
    svec8 bx = __builtin_bit_cast(svec8, px);
    float xf[8];
    #pragma unroll
    for (int j = 0; j < 8; j++) xf[j] = pgetv(px, j);

    svec8 wb0 = ldfrag(&WTB[ln * 8]);
    svec8 wb1 = ldfrag(&WTB[512 + ln * 8]);
    fvec4 d0 = __builtin_amdgcn_mfma_f32_16x16x32_bf16(wb0, bx, zc, 0, 0, 0);
    fvec4 d1 = __builtin_amdgcn_mfma_f32_16x16x32_bf16(wb1, bx, zc, 0, 0, 0);
    float v[8];
    #pragma unroll
    for (int j = 0; j < 4; j++) { v[j] = d0[j]; v[4 + j] = d1[j]; }
    float S = 0.f, Sq = 0.f;
    #pragma unroll
    for (int j = 0; j < 8; j++) { S += v[j]; Sq = fmaf(v[j], v[j], Sq); }
    S  += __shfl_xor(S, 16);  Sq += __shfl_xor(Sq, 16);
    S  += __shfl_xor(S, 32);  Sq += __shfl_xor(Sq, 32);
    float mean = S * (1.f / 32.f);
    float var = fmaxf(Sq * (1.f / 32.f) - mean * mean, 0.f);
    float rs = rsqrtf(var + 1e-5f);
    uvec4 pg1 = P4[Q], pb1 = P4[4 + Q];
    float n[8];
    #pragma unroll
    for (int j = 0; j < 8; j++)
        n[j] = (v[j] - mean) * rs * pgetv(pg1, j) + pgetv(pb1, j);
    uvec4 tu;
    tu[0] = cvtpk(n[0], n[1]); tu[1] = cvtpk(n[2], n[3]);
    tu[2] = cvtpk(n[4], n[5]); tu[3] = cvtpk(n[6], n[7]);
    svec8 tf = __builtin_bit_cast(svec8, tu);
    svec8 a1f0 = ldfrag(&WTB[1024 + ln * 8]);
    svec8 a1f1 = ldfrag(&WTB[1536 + ln * 8]);
    fvec4 u0 = __builtin_amdgcn_mfma_f32_16x16x32_bf16(a1f0, tf, zc, 0, 0, 0);
    fvec4 u1 = __builtin_amdgcn_mfma_f32_16x16x32_bf16(a1f1, tf, zc, 0, 0, 0);
    uvec4 pc1 = P4[16 + Q];
    uvec4 uu;
    uu[0] = cvtpk(fmaxf(u0[0] + pgetv(pc1, 0), 0.f), fmaxf(u0[1] + pgetv(pc1, 1), 0.f));
    uu[1] = cvtpk(fmaxf(u0[2] + pgetv(pc1, 2), 0.f), fmaxf(u0[3] + pgetv(pc1, 3), 0.f));
    uu[2] = cvtpk(fmaxf(u1[0] + pgetv(pc1, 4), 0.f), fmaxf(u1[1] + pgetv(pc1, 5), 0.f));
    uu[3] = cvtpk(fmaxf(u1[2] + pgetv(pc1, 6), 0.f), fmaxf(u1[3] + pgetv(pc1, 7), 0.f));
    svec8 uf = __builtin_bit_cast(svec8, uu);
    svec8 a2f0 = ldfrag(&WTB[2048 + ln * 8]);
    svec8 a2f1 = ldfrag(&WTB[2560 + ln * 8]);
    fvec4 g0 = __builtin_amdgcn_mfma_f32_16x16x32_bf16(a2f0, uf, zc, 0, 0, 0);
    fvec4 g1 = __builtin_amdgcn_mfma_f32_16x16x32_bf16(a2f1, uf, zc, 0, 0, 0);
    uvec4 pc2 = P4[20 + Q];
    #pragma unroll
    for (int j = 0; j < 8; j++)
        v[j] = (j < 4 ? g0[j] : g1[j - 4]) + pgetv(pc2, j) + xf[j];
    float S2 = 0.f, Sq2 = 0.f;
    #pragma unroll
    for (int j = 0; j < 8; j++) { S2 += v[j]; Sq2 = fmaf(v[j], v[j], Sq2); }
    S2  += __shfl_xor(S2, 16);  Sq2 += __shfl_xor(Sq2, 16);
    S2  += __shfl_xor(S2, 32);  Sq2 += __shfl_xor(Sq2, 32);
    float mean2 = S2 * (1.f / 32.f);
    float var2 = fmaxf(Sq2 * (1.f / 32.f) - mean2 * mean2, 0.f);
    float rs2 = rsqrtf(var2 + 1e-5f);
    uvec4 pg2 = P4[8 + Q], pb2 = P4[12 + Q];
    float n2[8];
    #pragma unroll
    for (int j = 0; j < 8; j++)
        n2[j] = (v[j] - mean2) * rs2 * pgetv(pg2, j) + pgetv(pb2, j);
    uvec4 t2u;
    t2u[0] = cvtpk(n2[0], n2[1]); t2u[1] = cvtpk(n2[2], n2[3]);
    t2u[2] = cvtpk(n2[4], n2[5]); t2u[3] = cvtpk(n2[6], n2[7]);
    svec8 t2 = __builtin_bit_cast(svec8, t2u);
    svec8 a3f0 = ldfrag(&WTB[3072 + ln * 8]);
    svec8 a3f1 = ldfrag(&WTB[3584 + ln * 8]);
    fvec4 q0 = __builtin_amdgcn_mfma_f32_16x16x32_bf16(a3f0, t2, zc, 0, 0, 0);
    fvec4 q1 = __builtin_amdgcn_mfma_f32_16x16x32_bf16(a3f1, t2, zc, 0, 0, 0);
    uvec4 pc3 = P4[24 + Q], pw2 = P4[28 + Q];
    float yp = 0.f;
    #pragma unroll
    for (int j = 0; j < 8; j++) {
        float ee = (j < 4 ? q0[j] : q1[j - 4]) + pgetv(pc3, j);
        yp = fmaf(pgetv(pw2, j), fmaxf(ee, 0.f), yp);
    }
    yp += __shfl_xor(yp, 16); yp += __shfl_xor(yp, 32);
    return yp;
}

// ======================= KERNEL B-lite: pipeline from stored X ============
__global__ __launch_bounds__(NTHR, 8) void pipeline_lite_kernel(
    const float* __restrict__ ln1g,const float* __restrict__ ln1b,
    const float* __restrict__ ln2g,const float* __restrict__ ln2b,
    const float* __restrict__ f1w1,const float* __restrict__ f1b1,
    const float* __restrict__ f1w2,const float* __restrict__ f1b2,
    const float* __restrict__ f2w1,const float* __restrict__ f2b1,
    const float* __restrict__ f2w2,const float* __restrict__ f2b2,
    const unsigned short* __restrict__ wsWb, const uvec4* __restrict__ wsX,
    float* __restrict__ out)
{
    const int b   = blockIdx.x;
    const int tid = threadIdx.x;
    const int w   = tid >> 6;
    const int ln  = tid & 63;
    const int tk  = ln & 15;
    const int Q   = ln >> 4;

    __shared__ unsigned short WTB[4 * 1024] __attribute__((aligned(16))); // 8192 B
    __shared__ unsigned PCK[128] __attribute__((aligned(16)));            //  512 B
    __shared__ float red[NW * 3];

    for (int idx = tid; idx < 4096; idx += NTHR) {
        int f = idx >> 9, lane = (idx >> 3) & 63, j = idx & 7;
        int tkk = lane & 15, QQ = lane >> 4;
        int Lr = ((tkk >> 2) * 8) + (tkk & 3) + (f & 1) * 4;
        int col = QQ * 8 + j;
        int wsel = f >> 1;
        unsigned short vbf;
        if      (wsel == 0) vbf = wsWb[(size_t)b * 1024 + Lr * 32 + col];
        else if (wsel == 1) vbf = f2bf(f1w1[Lr * 32 + col]);
        else if (wsel == 2) vbf = f2bf(f1w2[Lr * 32 + col]);
        else                vbf = f2bf(f2w1[Lr * 32 + col]);
        WTB[idx] = vbf;
    }
    if (tid < 128) {
        int t8 = tid >> 4, q = (tid >> 2) & 3, i = tid & 3, f = q * 8 + 2 * i;
        const float* sp;
        if      (t8 == 0) sp = ln1g;
        else if (t8 == 1) sp = ln1b;
        else if (t8 == 2) sp = ln2g;
        else if (t8 == 3) sp = ln2b;
        else if (t8 == 4) sp = f1b1;
        else if (t8 == 5) sp = f1b2;
        else if (t8 == 6) sp = f2b1;
        else              sp = f2w2;
        PCK[tid] = pk2(sp[f], sp[f + 1]);
    }
    __syncthreads();

    const float ybias = f2b2[0];
    const uvec4* P4 = (const uvec4*)PCK;

    float s0 = 0.f, s1 = 0.f, s2 = 0.f;
    for (int t = w; t < NTILE; t += NW) {
        uvec4 px = wsX[((size_t)b * NTILE + t) * 64 + tk * 4 + Q];
        float yp = pipe_tile(px, WTB, P4, ln, Q);
        if (Q == 0) {
            const int sg = (t >= NSEG) ? 1 : 0;
            const int tl = (sg ? (t - NSEG) : t) * 16 + tk;
            float yv = yp + ybias;
            if (sg == 0) { if (tl < L0T) s0 += yv; }
            else {
                if (tl < L1T)       s1 += yv;
                else if (tl == L1T) s2 += yv;
            }
        }
    }

    s0 += __shfl_xor(s0, 1); s0 += __shfl_xor(s0, 2);
    s0 += __shfl_xor(s0, 4); s0 += __shfl_xor(s0, 8);
    s1 += __shfl_xor(s1, 1); s1 += __shfl_xor(s1, 2);
    s1 += __shfl_xor(s1, 4); s1 += __shfl_xor(s1, 8);
    s2 += __shfl_xor(s2, 1); s2 += __shfl_xor(s2, 2);
    s2 += __shfl_xor(s2, 4); s2 += __shfl_xor(s2, 8);
    if (ln == 0) { red[w * 3] = s0; red[w * 3 + 1] = s1; red[w * 3 + 2] = s2; }
    __syncthreads();
    if (tid == 0) {
        float a0 = 0.f, a1 = 0.f, a2 = 0.f;
        #pragma unroll
        for (int k = 0; k < NW; k++) {
            a0 += red[k * 3]; a1 += red[k * 3 + 1]; a2 += red[k * 3 + 2];
        }
        out[b] = a0 / (float)L0T + a1 / (float)L1T + a2;
    }
}

// ======================= KERNEL B-full: fallback (recompute embed) ========
__global__ __launch_bounds__(NTHR, 8) void pipeline_full_kernel(
    const float* __restrict__ x0,  const float* __restrict__ x1,
    const float* __restrict__ pos0,const float* __restrict__ pos1,
    const float* __restrict__ e0w1,const float* __restrict__ e0b1,
    const float* __restrict__ e0w2,const float* __restrict__ e0b2,
    const float* __restrict__ e1w1,const float* __restrict__ e1b1,
    const float* __restrict__ e1w2,const float* __restrict__ e1b2,
    const float* __restrict__ ln1g,const float* __restrict__ ln1b,
    const float* __restrict__ ln2g,const float* __restrict__ ln2b,
    const float* __restrict__ f1w1,const float* __restrict__ f1b1,
    const float* __restrict__ f1w2,const float* __restrict__ f1b2,
    const float* __restrict__ f2w1,const float* __restrict__ f2b1,
    const float* __restrict__ f2w2,const float* __restrict__ f2b2,
    const unsigned short* __restrict__ wsWb, const float* __restrict__ wsEC,
    float* __restrict__ out)
{
    const int b   = blockIdx.x;
    const int tid = threadIdx.x;
    const int w   = tid >> 6;
    const int ln  = tid & 63;
    const int tk  = ln & 15;
    const int Q   = ln >> 4;

    __shared__ unsigned short TBL[4 * 1024] __attribute__((aligned(16)));
    __shared__ unsigned short WTB[4 * 1024] __attribute__((aligned(16)));
    __shared__ float BIA[128] __attribute__((aligned(16)));
    __shared__ unsigned PCK[128] __attribute__((aligned(16)));
    __shared__ float ECV[32] __attribute__((aligned(16)));
    __shared__ float red[NW * 3];

    float4 pwr;
    pwr.x = 0.5f / (float)(Q * 4 + 1);
    pwr.y = 0.5f / (float)(Q * 4 + 2);
    pwr.z = 0.5f / (float)(Q * 4 + 3);
    pwr.w = 0.5f / (float)(Q * 4 + 4);

    for (int idx = tid; idx < 1024; idx += NTHR) {
        int f = idx >> 9, lane = (idx >> 3) & 63, j = idx & 7;
        int tkk = lane & 15, QQ = lane >> 4;
        int Lr = ((tkk >> 2) * 8) + (tkk & 3) + f * 4;
        int col = QQ * 8 + j;
        TBL[idx]        = (col < 8)  ? f2bf(e0w1[Lr * 8  + col]) : (unsigned short)0;
        TBL[1024 + idx] = f2bf(e0w2[Lr * 32 + col]);
        TBL[2048 + idx] = (col < 16) ? f2bf(e1w1[Lr * 16 + col]) : (unsigned short)0;
        TBL[3072 + idx] = f2bf(e1w2[Lr * 32 + col]);
    }
    for (int idx = tid; idx < 4096; idx += NTHR) {
        int f = idx >> 9, lane = (idx >> 3) & 63, j = idx & 7;
        int tkk = lane & 15, QQ = lane >> 4;
        int Lr = ((tkk >> 2) * 8) + (tkk & 3) + (f & 1) * 4;
        int col = QQ * 8 + j;
        int wsel = f >> 1;
        unsigned short vbf;
        if      (wsel == 0) vbf = wsWb[(size_t)b * 1024 + Lr * 32 + col];
        else if (wsel == 1) vbf = f2bf(f1w1[Lr * 32 + col]);
        else if (wsel == 2) vbf = f2bf(f1w2[Lr * 32 + col]);
        else                vbf = f2bf(f2w1[Lr * 32 + col]);
        WTB[idx] = vbf;
    }
    if (tid < 128) {
        int s = tid >> 5, i = tid & 31;
        float bv;
        if      (s == 0) bv = e0b1[i];
        else if (s == 1) bv = e0b2[i];
        else if (s == 2) bv = e1b1[i];
        else             bv = e1b2[i];
        BIA[tid] = bv;
    }
    if (tid < 128) {
        int t8 = tid >> 4, q = (tid >> 2) & 3, i = tid & 3, f = q * 8 + 2 * i;
        const float* sp;
        if      (t8 == 0) sp = ln1g;
        else if (t8 == 1) sp = ln1b;
        else if (t8 == 2) sp = ln2g;
        else if (t8 == 3) sp = ln2b;
        else if (t8 == 4) sp = f1b1;
        else if (t8 == 5) sp = f1b2;
        else if (t8 == 6) sp = f2b1;
        else              sp = f2w2;
        PCK[tid] = pk2(sp[f], sp[f + 1]);
    }
    if (tid < 32) ECV[tid] = wsEC[(size_t)b * 32 + tid];
    __syncthreads();

    const float ybias = f2b2[0];
    const uvec4* P4 = (const uvec4*)PCK;

    float s0 = 0.f, s1 = 0.f, s2 = 0.f;
    for (int t = w; t < NTILE; t += NW) {
        svec8 bx0; float pv; int sg, tl;
        load_tile(t, b, tk, Q, x0, x1, pos0, pos1, bx0, pv, sg, tl);
        float e[8];
        {
            const unsigned short* T = TBL + sg * 2048;
            const float* Bb = BIA + sg * 64;
            embed_pass(T, T + 1024, Bb, Bb + 32, bx0, ln, Q, e);
        }
        float xv[8]; finish_xv(sg, tl, Q, e, pv, pwr, ECV, xv);
        uvec4 pkx;
        pkx[0] = cvtpk(xv[0], xv[1]); pkx[1] = cvtpk(xv[2], xv[3]);
        pkx[2] = cvtpk(xv[4], xv[5]); pkx[3] = cvtpk(xv[6], xv[7]);
        float yp = pipe_tile(pkx, WTB, P4, ln, Q);
        if (Q == 0) {
            float yv = yp + ybias;
            if (sg == 0) { if (tl < L0T) s0 += yv; }
            else {
                if (tl < L1T)       s1 += yv;
                else if (tl == L1T) s2 += yv;
            }
        }
    }

    s0 += __shfl_xor(s0, 1); s0 += __shfl_xor(s0, 2);
    s0 += __shfl_xor(s0, 4); s0 += __shfl_xor(s0, 8);
    s1 += __shfl_xor(s1, 1); s1 += __shfl_xor(s1, 2);
    s1 += __shfl_xor(s1, 4); s1 += __shfl_xor(s1, 8);
    s2 += __shfl_xor(s2, 1); s2 += __shfl_xor(s2, 2);
    s2 += __shfl_xor(s2, 4); s2 += __shfl_xor(s2, 8);
    if (ln == 0) { red[w * 3] = s0; red[w * 3 + 1] = s1; red[w * 3 + 2] = s2; }
    __syncthreads();
    if (tid == 0) {
        float a0 = 0.f, a1 = 0.f, a2 = 0.f;
        #pragma unroll
        for (int k = 0; k < NW; k++) {
            a0 += red[k * 3]; a1 += red[k * 3 + 1]; a2 += red[k * 3 + 2];
        }
        out[b] = a0 / (float)L0T + a1 / (float)L1T + a2;
    }
}

extern "C" void kernel_launch(void* const* d_in, const int* in_sizes, int n_in,
                              void* d_out, int out_size, void* d_ws, size_t ws_size,
                              hipStream_t stream)
{
    const float* x0   = (const float*)d_in[0];
    const float* x1   = (const float*)d_in[1];
    const float* pos0 = (const float*)d_in[2];
    const float* pos1 = (const float*)d_in[3];
    const float* xcT  = (const float*)d_in[4];
    const float* e0w1 = (const float*)d_in[5];
    const float* e0b1 = (const float*)d_in[6];
    const float* e0w2 = (const float*)d_in[7];
    const float* e0b2 = (const float*)d_in[8];
    const float* e1w1 = (const float*)d_in[9];
    const float* e1b1 = (const float*)d_in[10];
    const float* e1w2 = (const float*)d_in[11];
    const float* e1b2 = (const float*)d_in[12];
    const float* ecw1 = (const float*)d_in[13];
    const float* ecb1 = (const float*)d_in[14];
    const float* ecw2 = (const float*)d_in[15];
    const float* ecb2 = (const float*)d_in[16];
    const float* wq   = (const float*)d_in[17];
    const float* wk   = (const float*)d_in[18];
    const float* wv   = (const float*)d_in[19];
    const float* wo   = (const float*)d_in[20];
    const float* ln1g = (const float*)d_in[21];
    const float* ln1b = (const float*)d_in[22];
    const float* ln2g = (const float*)d_in[23];
    const float* ln2b = (const float*)d_in[24];
    const float* f1w1 = (const float*)d_in[25];
    const float* f1b1 = (const float*)d_in[26];
    const float* f1w2 = (const float*)d_in[27];
    const float* f1b2 = (const float*)d_in[28];
    const float* f2w1 = (const float*)d_in[29];
    const float* f2b1 = (const float*)d_in[30];
    const float* f2w2 = (const float*)d_in[31];
    const float* f2b2 = (const float*)d_in[32];
    float* out = (float*)d_out;

    const int B = in_sizes[0] / (L0T * 8);

    unsigned short* wsWb = (unsigned short*)d_ws;                  // B*1024 bf16
    float* wsEC = (float*)((char*)d_ws + (size_t)B * 1024 * 2);    // B*32 f32
    size_t offX = (size_t)B * 1024 * 2 + (size_t)B * 32 * 4;
    size_t needX = offX + (size_t)B * NTILE * 64 * 16;             // B*46*64 uvec4
    const bool lite = (ws_size >= needX);
    uvec4* wsX = lite ? (uvec4*)((char*)d_ws + offX) : (uvec4*)nullptr;

    hipLaunchKernelGGL(embed_gram_kernel, dim3(B), dim3(NTHR), 0, stream,
                       x0, x1, pos0, pos1, xcT,
                       e0w1, e0b1, e0w2, e0b2, e1w1, e1b1, e1w2, e1b2,
                       ecw1, ecb1, ecw2, ecb2, wq, wk, wv, wo,
                       wsWb, wsEC, wsX);
    if (lite) {
        hipLaunchKernelGGL(pipeline_lite_kernel, dim3(B), dim3(NTHR), 0, stream,
                           ln1g, ln1b, ln2g, ln2b,
                           f1w1, f1b1, f1w2, f1b2, f2w1, f2b1, f2w2, f2b2,
                           wsWb, wsX, out);
    } else {
        hipLaunchKernelGGL(pipeline_full_kernel, dim3(B), dim3(NTHR), 0, stream,
                           x0, x1, pos0, pos1,
                           e0w1, e0b1, e0w2, e0b2, e1w1, e1b1, e1w2, e1b2,
                           ln1g, ln1b, ln2g, ln2b,
                           f1w1, f1b1, f1w2, f1b2, f2w1, f2b1, f2w2, f2b2,
                           wsWb, wsEC, out);
    }
}

// Round 14
// 287.226 us; speedup vs baseline: 1.6147x; 1.0859x over previous
//
#include <hip/hip_runtime.h>
#include <math.h>

#define L0T 365
#define L1T 366
#define LT  732
#define NTILE 46
#define NSEG 23
#define NW   4
#define NTHR 256

// sched_barrier mask: bits = instruction classes ALLOWED to cross.
// DS excluded -> cross-lane LDS exchange order pinned, all else free.
#define SB_NO_DS 0x7F

typedef short svec8 __attribute__((ext_vector_type(8)));   // 8 bf16
typedef float fvec4 __attribute__((ext_vector_type(4)));
typedef float fvec16 __attribute__((ext_vector_type(16)));
typedef unsigned uvec4 __attribute__((ext_vector_type(4)));

__device__ __forceinline__ unsigned short f2bf(float f) {
    unsigned u = __float_as_uint(f);
    u = (u + 0x7fffu + ((u >> 16) & 1u)) >> 16;
    return (unsigned short)u;
}
__device__ __forceinline__ float bf2f(unsigned short s) {
    return __uint_as_float(((unsigned)s) << 16);
}
__device__ __forceinline__ unsigned pk2(float a, float b) {
    return (unsigned)f2bf(a) | ((unsigned)f2bf(b) << 16);
}
__device__ __forceinline__ unsigned cvtpk(float a, float b) {
    unsigned r;
    asm("v_cvt_pk_bf16_f32 %0, %1, %2" : "=v"(r) : "v"(a), "v"(b));
    return r;
}
__device__ __forceinline__ float pgetv(uvec4 p, int j) {
    unsigned u = p[j >> 1];
    return bf2f((unsigned short)((j & 1) ? (u >> 16) : (u & 0xffffu)));
}
__device__ __forceinline__ svec8 pack8(float4 a, float4 c) {
    uvec4 u;
    u[0] = cvtpk(a.x, a.y); u[1] = cvtpk(a.z, a.w);
    u[2] = cvtpk(c.x, c.y); u[3] = cvtpk(c.z, c.w);
    return __builtin_bit_cast(svec8, u);
}
// posenc via HW transcendentals (input in REVOLUTIONS)
__device__ __forceinline__ void fastsc(float rev, float& s, float& c) {
    float fr;
    asm("v_fract_f32 %0, %1" : "=v"(fr) : "v"(rev));
    asm("v_sin_f32 %0, %1"   : "=v"(s)  : "v"(fr));
    asm("v_cos_f32 %0, %1"   : "=v"(c)  : "v"(fr));
}
// Opaque-pointer LDS load: LICM cannot hoist (R4 failure mode defeated).
__device__ __forceinline__ svec8 ldfrag(const unsigned short* p) {
    asm volatile("" : "+v"(p));
    return *(const svec8*)p;
}

// 2-layer embed MLP for a 16-token tile; tables in LANE ORDER
// ([2 frag][64 lane][8 bf16] -> ds_read_b128 at lane*16B, conflict-free),
// biases folded into the MFMA C operand.
__device__ __forceinline__ void embed_pass(
    const unsigned short* __restrict__ T1,
    const unsigned short* __restrict__ T2,
    const float* __restrict__ Bh, const float* __restrict__ Bx,
    svec8 bx, int ln, int Q, float* __restrict__ out)
{
    svec8 w1f0 = *(const svec8*)&T1[ln * 8];
    svec8 w1f1 = *(const svec8*)&T1[512 + ln * 8];
    const fvec4* bh = (const fvec4*)&Bh[Q * 8];
    fvec4 d0 = __builtin_amdgcn_mfma_f32_16x16x32_bf16(w1f0, bx, bh[0], 0, 0, 0);
    fvec4 d1 = __builtin_amdgcn_mfma_f32_16x16x32_bf16(w1f1, bx, bh[1], 0, 0, 0);
    uvec4 hu;
    hu[0] = cvtpk(fmaxf(d0[0], 0.f), fmaxf(d0[1], 0.f));
    hu[1] = cvtpk(fmaxf(d0[2], 0.f), fmaxf(d0[3], 0.f));
    hu[2] = cvtpk(fmaxf(d1[0], 0.f), fmaxf(d1[1], 0.f));
    hu[3] = cvtpk(fmaxf(d1[2], 0.f), fmaxf(d1[3], 0.f));
    svec8 hf = __builtin_bit_cast(svec8, hu);
    svec8 w2f0 = *(const svec8*)&T2[ln * 8];
    svec8 w2f1 = *(const svec8*)&T2[512 + ln * 8];
    const fvec4* bb = (const fvec4*)&Bx[Q * 8];
    fvec4 g0 = __builtin_amdgcn_mfma_f32_16x16x32_bf16(w2f0, hf, bb[0], 0, 0, 0);
    fvec4 g1 = __builtin_amdgcn_mfma_f32_16x16x32_bf16(w2f1, hf, bb[1], 0, 0, 0);
    out[0] = g0[0]; out[1] = g0[1]; out[2] = g0[2]; out[3] = g0[3];
    out[4] = g1[0]; out[5] = g1[1]; out[6] = g1[2]; out[7] = g1[3];
}

// Per-SEGMENT tiling: t<23 -> x0 tokens t*16+tk (<365); t>=23 -> x1 tokens
// (t-23)*16+tk (<366), slot 366 = xc token (ECV), slot 367 = zero.
__device__ __forceinline__ void load_tile(
    int t, int b, int tk, int Q,
    const float* __restrict__ x0, const float* __restrict__ x1,
    const float* __restrict__ pos0, const float* __restrict__ pos1,
    svec8& bx, float& pv, int& seg, int& tl)
{
    seg = (t >= NSEG) ? 1 : 0;
    tl  = (seg ? (t - NSEG) : t) * 16 + tk;
    const int lim = seg ? L1T : L0T;
    const bool tvalid = tl < lim;
    #pragma unroll
    for (int j = 0; j < 8; j++) bx[j] = 0;
    const bool ld = tvalid && (seg ? (Q < 2) : (Q == 0));
    if (ld) {
        const float4* px = seg
            ? (const float4*)(x1 + ((size_t)b * L1T + tl) * 16 + Q * 8)
            : (const float4*)(x0 + ((size_t)b * L0T + tl) * 8);
        bx = pack8(px[0], px[1]);
    }
    pv = 0.f;
    if (tvalid) pv = seg ? pos1[(size_t)b * L1T + tl] : pos0[(size_t)b * L0T + tl];
}

__device__ __forceinline__ void finish_xv(
    int seg, int tl, int Q, const float* __restrict__ e, float pv, float4 pwr,
    const float* __restrict__ ECV, float* __restrict__ xv)
{
    const int lim = seg ? L1T : L0T;
    const bool tvalid = tl < lim;
    const bool isxc = seg && (tl == L1T);
    const float pwa[4] = {pwr.x, pwr.y, pwr.z, pwr.w};
    #pragma unroll
    for (int j = 0; j < 8; j += 2) {
        float s, c; fastsc(pv * pwa[j >> 1], s, c);
        float a0 = e[j] + s, a1 = e[j + 1] + c;
        xv[j]     = tvalid ? a0 : (isxc ? ECV[Q * 8 + j]     : 0.f);
        xv[j + 1] = tvalid ? a1 : (isxc ? ECV[Q * 8 + j + 1] : 0.f);
    }
}

// ======================= KERNEL A: embed + Gram + attention ===============
// R14 = exact revert to the proven R11 structure (best: A ~100us, no spill).
// R12's pair-processing and R13's raw-input prefetch both spilled: the
// 64-total-reg budget here has ~zero headroom (even +9 regs spills).
// Persists each tile's bf16 X (the staged pk) to wsX so kernel B need not
// recompute embed.
__global__ __launch_bounds__(NTHR, 8) void embed_gram_kernel(
    const float* __restrict__ x0,  const float* __restrict__ x1,
    const float* __restrict__ pos0,const float* __restrict__ pos1,
    const float* __restrict__ xcT,
    const float* __restrict__ e0w1,const float* __restrict__ e0b1,
    const float* __restrict__ e0w2,const float* __restrict__ e0b2,
    const float* __restrict__ e1w1,const float* __restrict__ e1b1,
    const float* __restrict__ e1w2,const float* __restrict__ e1b2,
    const float* __restrict__ ecw1,const float* __restrict__ ecb1,
    const float* __restrict__ ecw2,const float* __restrict__ ecb2,
    const float* __restrict__ wq,  const float* __restrict__ wk,
    const float* __restrict__ wv,  const float* __restrict__ wo,
    unsigned short* __restrict__ wsWb, float* __restrict__ wsEC,
    uvec4* __restrict__ wsX)
{
    const int b   = blockIdx.x;
    const int tid = threadIdx.x;
    const int w   = tid >> 6;
    const int ln  = tid & 63;
    const int tk  = ln & 15;
    const int Q   = ln >> 4;

    __shared__ unsigned short TBL[4 * 1024] __attribute__((aligned(16))); // 8192 B
    __shared__ float BIA[128] __attribute__((aligned(16)));               //  512 B
    __shared__ unsigned short SCB[2304] __attribute__((aligned(16)));     // 4608 B (STG | T1f)
    __shared__ float Cm[1024] __attribute__((aligned(16)));               // 4096 B
    __shared__ float ECV[32] __attribute__((aligned(16)));                //  128 B

    float* T1f = (float*)SCB;          // phase-2 scratch (aliases staging)

    float4 pwr;
    pwr.x = 0.5f / (float)(Q * 4 + 1);
    pwr.y = 0.5f / (float)(Q * 4 + 2);
    pwr.z = 0.5f / (float)(Q * 4 + 3);
    pwr.w = 0.5f / (float)(Q * 4 + 4);

    // ---- phase 0: tables + ec MLP ----
    for (int idx = tid; idx < 1024; idx += NTHR) {
        int f = idx >> 9, lane = (idx >> 3) & 63, j = idx & 7;
        int tkk = lane & 15, QQ = lane >> 4;
        int Lr = ((tkk >> 2) * 8) + (tkk & 3) + f * 4;
        int col = QQ * 8 + j;
        TBL[idx]        = (col < 8)  ? f2bf(e0w1[Lr * 8  + col]) : (unsigned short)0;
        TBL[1024 + idx] = f2bf(e0w2[Lr * 32 + col]);
        TBL[2048 + idx] = (col < 16) ? f2bf(e1w1[Lr * 16 + col]) : (unsigned short)0;
        TBL[3072 + idx] = f2bf(e1w2[Lr * 32 + col]);
        Cm[idx] = 0.f;
    }
    if (tid < 128) {
        int s = tid >> 5, i = tid & 31;
        float bv;
        if      (s == 0) bv = e0b1[i];
        else if (s == 1) bv = e0b2[i];
        else if (s == 2) bv = e1b1[i];
        else             bv = e1b2[i];
        BIA[tid] = bv;
    }
    float* ECH = T1f;
    if (tid >= 224) {
        int i = tid - 224;
        const float4* xr = (const float4*)(xcT + (size_t)b * 32);
        const float4* wr = (const float4*)&ecw1[i * 32];
        float a = ecb1[i];
        #pragma unroll
        for (int j4 = 0; j4 < 8; j4++) {
            float4 ww = wr[j4], xx = xr[j4];
            a = fmaf(ww.x, xx.x, a); a = fmaf(ww.y, xx.y, a);
            a = fmaf(ww.z, xx.z, a); a = fmaf(ww.w, xx.w, a);
        }
        ECH[i] = fmaxf(a, 0.f);
    }
    __syncthreads();
    if (tid >= 224) {
        int i = tid - 224;
        const float4* wr = (const float4*)&ecw2[i * 32];
        float a = ecb2[i];
        #pragma unroll
        for (int j4 = 0; j4 < 8; j4++) {
            float4 ww = wr[j4];
            a = fmaf(ww.x, ECH[j4 * 4 + 0], a); a = fmaf(ww.y, ECH[j4 * 4 + 1], a);
            a = fmaf(ww.z, ECH[j4 * 4 + 2], a); a = fmaf(ww.w, ECH[j4 * 4 + 3], a);
        }
        ECV[i] = a;
        wsEC[(size_t)b * 32 + i] = a;
    }
    __syncthreads();

    // ---- phase 1: embed + Gram (+ persist X) ----
    {
        const int feat = ln & 31, half = ln >> 5;
        const int wbase = w * 576;
        const int waddr = wbase + tk * 32 + (tk >> 3) * 32 + Q * 8;
        const int rbase = wbase + half * 288 + feat;
        fvec16 dG;
        #pragma unroll
        for (int i = 0; i < 16; i++) dG[i] = 0.f;
        for (int t = w; t < NTILE; t += NW) {
            svec8 bx; float pv; int sg, tl;
            load_tile(t, b, tk, Q, x0, x1, pos0, pos1, bx, pv, sg, tl);
            float e[8];
            {
                const unsigned short* T = TBL + sg * 2048;
                const float* Bb = BIA + sg * 64;
                embed_pass(T, T + 1024, Bb, Bb + 32, bx, ln, Q, e);
            }
            float xv[8]; finish_xv(sg, tl, Q, e, pv, pwr, ECV, xv);
            uvec4 pk;
            pk[0] = cvtpk(xv[0], xv[1]); pk[1] = cvtpk(xv[2], xv[3]);
            pk[2] = cvtpk(xv[4], xv[5]); pk[3] = cvtpk(xv[6], xv[7]);
            if (wsX)   // persist X for kernel B (coalesced 1KB/tile/wave)
                wsX[((size_t)b * NTILE + t) * 64 + tk * 4 + Q] = pk;
            // cross-lane LDS exchange: DS order pinned, all else may cross
            __builtin_amdgcn_sched_barrier(SB_NO_DS);
            *(uvec4*)&SCB[waddr] = pk;
            __builtin_amdgcn_sched_barrier(SB_NO_DS);
            svec8 af;
            #pragma unroll
            for (int j = 0; j < 8; j++)
                af[j] = (short)SCB[rbase + j * 32];
            __builtin_amdgcn_sched_barrier(SB_NO_DS);
            dG = __builtin_amdgcn_mfma_f32_32x32x16_bf16(af, af, dG, 0, 0, 0);
        }
        #pragma unroll
        for (int rg = 0; rg < 16; rg++) {
            int row = (rg & 3) + 8 * (rg >> 2) + 4 * half;
            atomicAdd(&Cm[row * 32 + feat], dG[rg]);
        }
    }
    __syncthreads();

    // ---- phase 2: attention collapse -> Wb to workspace ----
    for (int idx = tid; idx < 1024; idx += NTHR) {       // T1 = Cm * wk^T
        int i = idx >> 5, g = idx & 31;
        const float4* cr = (const float4*)&Cm[i * 32];
        const float4* wr = (const float4*)&wk[g * 32];
        float a = 0.f;
        #pragma unroll
        for (int j4 = 0; j4 < 8; j4++) {
            float4 cc = cr[j4], ww = wr[j4];
            a = fmaf(cc.x, ww.x, a); a = fmaf(cc.y, ww.y, a);
            a = fmaf(cc.z, ww.z, a); a = fmaf(cc.w, ww.w, a);
        }
        T1f[idx] = a;
    }
    __syncthreads();
    const float rsL = rsqrtf((float)LT);
    for (int idx = tid; idx < 1024; idx += NTHR) {       // T2 = wq * T1 (scaled)
        int h = idx >> 5, g = idx & 31;
        const float4* qr = (const float4*)&wq[h * 32];
        float a = 0.f;
        #pragma unroll
        for (int i4 = 0; i4 < 8; i4++) {
            float4 qq = qr[i4];
            a = fmaf(qq.x, T1f[(i4 * 4 + 0) * 32 + g], a);
            a = fmaf(qq.y, T1f[(i4 * 4 + 1) * 32 + g], a);
            a = fmaf(qq.z, T1f[(i4 * 4 + 2) * 32 + g], a);
            a = fmaf(qq.w, T1f[(i4 * 4 + 3) * 32 + g], a);
        }
        Cm[idx] = a * rsL;                               // Cm now holds T2
    }
    __syncthreads();
    {   // row softmax, 8 threads per row
        int r = tid >> 3, c0 = (tid & 7) * 4;
        float4 vv = *(const float4*)&Cm[r * 32 + c0];
        float m = fmaxf(fmaxf(vv.x, vv.y), fmaxf(vv.z, vv.w));
        m = fmaxf(m, __shfl_xor(m, 1));
        m = fmaxf(m, __shfl_xor(m, 2));
        m = fmaxf(m, __shfl_xor(m, 4));
        float ex = __expf(vv.x - m), ey = __expf(vv.y - m);
        float ez = __expf(vv.z - m), ew = __expf(vv.w - m);
        float s = ex + ey + ez + ew;
        s += __shfl_xor(s, 1); s += __shfl_xor(s, 2); s += __shfl_xor(s, 4);
        float inv = 1.f / s;
        float4 o; o.x = ex * inv; o.y = ey * inv; o.z = ez * inv; o.w = ew * inv;
        *(float4*)&Cm[r * 32 + c0] = o;
    }
    __syncthreads();
    for (int idx = tid; idx < 1024; idx += NTHR) {       // T1 = att * wv
        int h = idx >> 5, j = idx & 31;
        const float4* pr = (const float4*)&Cm[h * 32];
        float a = 0.f;
        #pragma unroll
        for (int g4 = 0; g4 < 8; g4++) {
            float4 pp = pr[g4];
            a = fmaf(pp.x, wv[(g4 * 4 + 0) * 32 + j], a);
            a = fmaf(pp.y, wv[(g4 * 4 + 1) * 32 + j], a);
            a = fmaf(pp.z, wv[(g4 * 4 + 2) * 32 + j], a);
            a = fmaf(pp.w, wv[(g4 * 4 + 3) * 32 + j], a);
        }
        T1f[idx] = a;
    }
    __syncthreads();
    for (int idx = tid; idx < 1024; idx += NTHR) {       // Wb = wo*T1 + I -> ws
        int o = idx >> 5, j = idx & 31;
        const float4* orow = (const float4*)&wo[o * 32];
        float a = 0.f;
        #pragma unroll
        for (int h4 = 0; h4 < 8; h4++) {
            float4 oo = orow[h4];
            a = fmaf(oo.x, T1f[(h4 * 4 + 0) * 32 + j], a);
            a = fmaf(oo.y, T1f[(h4 * 4 + 1) * 32 + j], a);
            a = fmaf(oo.z, T1f[(h4 * 4 + 2) * 32 + j], a);
            a = fmaf(oo.w, T1f[(h4 * 4 + 3) * 32 + j], a);
        }
        wsWb[(size_t)b * 1024 + idx] = f2bf(a + (o == j ? 1.f : 0.f));
    }
}

// Shared pipeline tail: Wb->LN1->FFN1->LN2->FFN2 for one tile from px.
__device__ __forceinline__ float pipe_tile(
    uvec4 px, const unsigned short* __restrict__ WTB, const uvec4* __restrict__ P4,
    int ln, int Q)
{
    const fvec4 zc = {0.f, 0.f, 0.f, 0.f};
    svec8 bx = __builtin_bit_cast(svec8, px);
    float xf[8];
    #pragma unroll
    for (int j = 0; j < 8; j++) xf[j] = pgetv(px, j);

    svec8 wb0 = ldfrag(&WTB[ln * 8]);
    svec8 wb1 = ldfrag(&WTB[512 + ln * 8]);
    fvec4 d0 = __builtin_amdgcn_mfma_f32_16x16x32_bf16(wb0, bx, zc, 0, 0, 0);
    fvec4 d1 = __builtin_amdgcn_mfma_f32_16x16x32_bf16(wb1, bx, zc, 0, 0, 0);
    float v[8];
    #pragma unroll
    for (int j = 0; j < 4; j++) { v[j] = d0[j]; v[4 + j] = d1[j]; }
    float S = 0.f, Sq = 0.f;
    #pragma unroll
    for (int j = 0; j < 8; j++) { S += v[j]; Sq = fmaf(v[j], v[j], Sq); }
    S  += __shfl_xor(S, 16);  Sq += __shfl_xor(Sq, 16);
    S  += __shfl_xor(S, 32);  Sq += __shfl_xor(Sq, 32);
    float mean = S * (1.f / 32.f);
    float var = fmaxf(Sq * (1.f / 32.f) - mean * mean, 0.f);
    float rs = rsqrtf(var + 1e-5f);
    uvec4 pg1 = P4[0 + Q], pb1 = P4[4 + Q];
    float n[8];
    #pragma unroll
    for (int j = 0; j < 8; j++)
        n[j] = (v[j] - mean) * rs * pgetv(pg1, j) + pgetv(pb1, j);
    uvec4 tu;
    tu[0] = cvtpk(n[0], n[1]); tu[1] = cvtpk(n[2], n[3]);
    tu[2] = cvtpk(n[4], n[5]); tu[3] = cvtpk(n[6], n[7]);
    svec8 tf = __builtin_bit_cast(svec8, tu);
    svec8 a1f0 = ldfrag(&WTB[1024 + ln * 8]);
    svec8 a1f1 = ldfrag(&WTB[1536 + ln * 8]);
    fvec4 u0 = __builtin_amdgcn_mfma_f32_16x16x32_bf16(a1f0, tf, zc, 0, 0, 0);
    fvec4 u1 = __builtin_amdgcn_mfma_f32_16x16x32_bf16(a1f1, tf, zc, 0, 0, 0);
    uvec4 pc1 = P4[16 + Q];
    uvec4 uu;
    uu[0] = cvtpk(fmaxf(u0[0] + pgetv(pc1, 0), 0.f), fmaxf(u0[1] + pgetv(pc1, 1), 0.f));
    uu[1] = cvtpk(fmaxf(u0[2] + pgetv(pc1, 2), 0.f), fmaxf(u0[3] + pgetv(pc1, 3), 0.f));
    uu[2] = cvtpk(fmaxf(u1[0] + pgetv(pc1, 4), 0.f), fmaxf(u1[1] + pgetv(pc1, 5), 0.f));
    uu[3] = cvtpk(fmaxf(u1[2] + pgetv(pc1, 6), 0.f), fmaxf(u1[3] + pgetv(pc1, 7), 0.f));
    svec8 uf = __builtin_bit_cast(svec8, uu);
    svec8 a2f0 = ldfrag(&WTB[2048 + ln * 8]);
    svec8 a2f1 = ldfrag(&WTB[2560 + ln * 8]);
    fvec4 g0 = __builtin_amdgcn_mfma_f32_16x16x32_bf16(a2f0, uf, zc, 0, 0, 0);
    fvec4 g1 = __builtin_amdgcn_mfma_f32_16x16x32_bf16(a2f1, uf, zc, 0, 0, 0);
    uvec4 pc2 = P4[20 + Q];
    #pragma unroll
    for (int j = 0; j < 8; j++)
        v[j] = (j < 4 ? g0[j] : g1[j - 4]) + pgetv(pc2, j) + xf[j];
    float S2 = 0.f, Sq2 = 0.f;
    #pragma unroll
    for (int j = 0; j < 8; j++) { S2 += v[j]; Sq2 = fmaf(v[j], v[j], Sq2); }
    S2  += __shfl_xor(S2, 16);  Sq2 += __shfl_xor(Sq2, 16);
    S2  += __shfl_xor(S2, 32);  Sq2 += __shfl_xor(Sq2, 32);
    float mean2 = S2 * (1.f / 32.f);
    float var2 = fmaxf(Sq2 * (1.f / 32.f) - mean2 * mean2, 0.f);
    float rs2 = rsqrtf(var2 + 1e-5f);
    uvec4 pg2 = P4[8 + Q], pb2 = P4[12 + Q];
    float n2[8];
    #pragma unroll
    for (int j = 0; j < 8; j++)
        n2[j] = (v[j] - mean2) * rs2 * pgetv(pg2, j) + pgetv(pb2, j);
    uvec4 t2u;
    t2u[0] = cvtpk(n2[0], n2[1]); t2u[1] = cvtpk(n2[2], n2[3]);
    t2u[2] = cvtpk(n2[4], n2[5]); t2u[3] = cvtpk(n2[6], n2[7]);
    svec8 t2 = __builtin_bit_cast(svec8, t2u);
    svec8 a3f0 = ldfrag(&WTB[3072 + ln * 8]);
    svec8 a3f1 = ldfrag(&WTB[3584 + ln * 8]);
    fvec4 q0 = __builtin_amdgcn_mfma_f32_16x16x32_bf16(a3f0, t2, zc, 0, 0, 0);
    fvec4 q1 = __builtin_amdgcn_mfma_f32_16x16x32_bf16(a3f1, t2, zc, 0, 0, 0);
    uvec4 pc3 = P4[24 + Q], pw2 = P4[28 + Q];
    float yp = 0.f;
    #pragma unroll
    for (int j = 0; j < 8; j++) {
        float ee = (j < 4 ? q0[j] : q1[j - 4]) + pgetv(pc3, j);
        yp = fmaf(pgetv(pw2, j), fmaxf(ee, 0.f), yp);
    }
    yp += __shfl_xor(yp, 16); yp += __shfl_xor(yp, 32);
    return yp;
}

// ======================= KERNEL B-lite: pipeline from stored X ============
__global__ __launch_bounds__(NTHR, 8) void pipeline_lite_kernel(
    const float* __restrict__ ln1g,const float* __restrict__ ln1b,
    const float* __restrict__ ln2g,const float* __restrict__ ln2b,
    const float* __restrict__ f1w1,const float* __restrict__ f1b1,
    const float* __restrict__ f1w2,const float* __restrict__ f1b2,
    const float* __restrict__ f2w1,const float* __restrict__ f2b1,
    const float* __restrict__ f2w2,const float* __restrict__ f2b2,
    const unsigned short* __restrict__ wsWb, const uvec4* __restrict__ wsX,
    float* __restrict__ out)
{
    const int b   = blockIdx.x;
    const int tid = threadIdx.x;
    const int w   = tid >> 6;
    const int ln  = tid & 63;
    const int tk  = ln & 15;
    const int Q   = ln >> 4;

    __shared__ unsigned short WTB[4 * 1024] __attribute__((aligned(16))); // 8192 B
    __shared__ unsigned PCK[128] __attribute__((aligned(16)));            //  512 B
    __shared__ float red[NW * 3];

    for (int idx = tid; idx < 4096; idx += NTHR) {
        int f = idx >> 9, lane = (idx >> 3) & 63, j = idx & 7;
        int tkk = lane & 15, QQ = lane >> 4;
        int Lr = ((tkk >> 2) * 8) + (tkk & 3) + (f & 1) * 4;
        int col = QQ * 8 + j;
        int wsel = f >> 1;
        unsigned short vbf;
        if      (wsel == 0) vbf = wsWb[(size_t)b * 1024 + Lr * 32 + col];
        else if (wsel == 1) vbf = f2bf(f1w1[Lr * 32 + col]);
        else if (wsel == 2) vbf = f2bf(f1w2[Lr * 32 + col]);
        else                vbf = f2bf(f2w1[Lr * 32 + col]);
        WTB[idx] = vbf;
    }
    if (tid < 128) {
        int t8 = tid >> 4, q = (tid >> 2) & 3, i = tid & 3, f = q * 8 + 2 * i;
        const float* sp;
        if      (t8 == 0) sp = ln1g;
        else if (t8 == 1) sp = ln1b;
        else if (t8 == 2) sp = ln2g;
        else if (t8 == 3) sp = ln2b;
        else if (t8 == 4) sp = f1b1;
        else if (t8 == 5) sp = f1b2;
        else if (t8 == 6) sp = f2b1;
        else              sp = f2w2;
        PCK[tid] = pk2(sp[f], sp[f + 1]);
    }
    __syncthreads();

    const float ybias = f2b2[0];
    const uvec4* P4 = (const uvec4*)PCK;

    float s0 = 0.f, s1 = 0.f, s2 = 0.f;
    for (int t = w; t < NTILE; t += NW) {
        uvec4 px = wsX[((size_t)b * NTILE + t) * 64 + tk * 4 + Q];
        float yp = pipe_tile(px, WTB, P4, ln, Q);
        if (Q == 0) {
            const int sg = (t >= NSEG) ? 1 : 0;
            const int tl = (sg ? (t - NSEG) : t) * 16 + tk;
            float yv = yp + ybias;
            if (sg == 0) { if (tl < L0T) s0 += yv; }
            else {
                if (tl < L1T)       s1 += yv;
                else if (tl == L1T) s2 += yv;
            }
        }
    }

    s0 += __shfl_xor(s0, 1); s0 += __shfl_xor(s0, 2);
    s0 += __shfl_xor(s0, 4); s0 += __shfl_xor(s0, 8);
    s1 += __shfl_xor(s1, 1); s1 += __shfl_xor(s1, 2);
    s1 += __shfl_xor(s1, 4); s1 += __shfl_xor(s1, 8);
    s2 += __shfl_xor(s2, 1); s2 += __shfl_xor(s2, 2);
    s2 += __shfl_xor(s2, 4); s2 += __shfl_xor(s2, 8);
    if (ln == 0) { red[w * 3] = s0; red[w * 3 + 1] = s1; red[w * 3 + 2] = s2; }
    __syncthreads();
    if (tid == 0) {
        float a0 = 0.f, a1 = 0.f, a2 = 0.f;
        #pragma unroll
        for (int k = 0; k < NW; k++) {
            a0 += red[k * 3]; a1 += red[k * 3 + 1]; a2 += red[k * 3 + 2];
        }
        out[b] = a0 / (float)L0T + a1 / (float)L1T + a2;
    }
}

// ======================= KERNEL B-full: fallback (recompute embed) ========
__global__ __launch_bounds__(NTHR, 8) void pipeline_full_kernel(
    const float* __restrict__ x0,  const float* __restrict__ x1,
    const float* __restrict__ pos0,const float* __restrict__ pos1,
    const float* __restrict__ e0w1,const float* __restrict__ e0b1,
    const float* __restrict__ e0w2,const float* __restrict__ e0b2,
    const float* __restrict__ e1w1,const float* __restrict__ e1b1,
    const float* __restrict__ e1w2,const float* __restrict__ e1b2,
    const float* __restrict__ ln1g,const float* __restrict__ ln1b,
    const float* __restrict__ ln2g,const float* __restrict__ ln2b,
    const float* __restrict__ f1w1,const float* __restrict__ f1b1,
    const float* __restrict__ f1w2,const float* __restrict__ f1b2,
    const float* __restrict__ f2w1,const float* __restrict__ f2b1,
    const float* __restrict__ f2w2,const float* __restrict__ f2b2,
    const unsigned short* __restrict__ wsWb, const float* __restrict__ wsEC,
    float* __restrict__ out)
{
    const int b   = blockIdx.x;
    const int tid = threadIdx.x;
    const int w   = tid >> 6;
    const int ln  = tid & 63;
    const int tk  = ln & 15;
    const int Q   = ln >> 4;

    __shared__ unsigned short TBL[4 * 1024] __attribute__((aligned(16)));
    __shared__ unsigned short WTB[4 * 1024] __attribute__((aligned(16)));
    __shared__ float BIA[128] __attribute__((aligned(16)));
    __shared__ unsigned PCK[128] __attribute__((aligned(16)));
    __shared__ float ECV[32] __attribute__((aligned(16)));
    __shared__ float red[NW * 3];

    float4 pwr;
    pwr.x = 0.5f / (float)(Q * 4 + 1);
    pwr.y = 0.5f / (float)(Q * 4 + 2);
    pwr.z = 0.5f / (float)(Q * 4 + 3);
    pwr.w = 0.5f / (float)(Q * 4 + 4);

    for (int idx = tid; idx < 1024; idx += NTHR) {
        int f = idx >> 9, lane = (idx >> 3) & 63, j = idx & 7;
        int tkk = lane & 15, QQ = lane >> 4;
        int Lr = ((tkk >> 2) * 8) + (tkk & 3) + f * 4;
        int col = QQ * 8 + j;
        TBL[idx]        = (col < 8)  ? f2bf(e0w1[Lr * 8  + col]) : (unsigned short)0;
        TBL[1024 + idx] = f2bf(e0w2[Lr * 32 + col]);
        TBL[2048 + idx] = (col < 16) ? f2bf(e1w1[Lr * 16 + col]) : (unsigned short)0;
        TBL[3072 + idx] = f2bf(e1w2[Lr * 32 + col]);
    }
    for (int idx = tid; idx < 4096; idx += NTHR) {
        int f = idx >> 9, lane = (idx >> 3) & 63, j = idx & 7;
        int tkk = lane & 15, QQ = lane >> 4;
        int Lr = ((tkk >> 2) * 8) + (tkk & 3) + (f & 1) * 4;
        int col = QQ * 8 + j;
        int wsel = f >> 1;
        unsigned short vbf;
        if      (wsel == 0) vbf = wsWb[(size_t)b * 1024 + Lr * 32 + col];
        else if (wsel == 1) vbf = f2bf(f1w1[Lr * 32 + col]);
        else if (wsel == 2) vbf = f2bf(f1w2[Lr * 32 + col]);
        else                vbf = f2bf(f2w1[Lr * 32 + col]);
        WTB[idx] = vbf;
    }
    if (tid < 128) {
        int s = tid >> 5, i = tid & 31;
        float bv;
        if      (s == 0) bv = e0b1[i];
        else if (s == 1) bv = e0b2[i];
        else if (s == 2) bv = e1b1[i];
        else             bv = e1b2[i];
        BIA[tid] = bv;
    }
    if (tid < 128) {
        int t8 = tid >> 4, q = (tid >> 2) & 3, i = tid & 3, f = q * 8 + 2 * i;
        const float* sp;
        if      (t8 == 0) sp = ln1g;
        else if (t8 == 1) sp = ln1b;
        else if (t8 == 2) sp = ln2g;
        else if (t8 == 3) sp = ln2b;
        else if (t8 == 4) sp = f1b1;
        else if (t8 == 5) sp = f1b2;
        else if (t8 == 6) sp = f2b1;
        else              sp = f2w2;
        PCK[tid] = pk2(sp[f], sp[f + 1]);
    }
    if (tid < 32) ECV[tid] = wsEC[(size_t)b * 32 + tid];
    __syncthreads();

    const float ybias = f2b2[0];
    const uvec4* P4 = (const uvec4*)PCK;

    float s0 = 0.f, s1 = 0.f, s2 = 0.f;
    for (int t = w; t < NTILE; t += NW) {
        svec8 bx0; float pv; int sg, tl;
        load_tile(t, b, tk, Q, x0, x1, pos0, pos1, bx0, pv, sg, tl);
        float e[8];
        {
            const unsigned short* T = TBL + sg * 2048;
            const float* Bb = BIA + sg * 64;
            embed_pass(T, T + 1024, Bb, Bb + 32, bx0, ln, Q, e);
        }
        float xv[8]; finish_xv(sg, tl, Q, e, pv, pwr, ECV, xv);
        uvec4 pkx;
        pkx[0] = cvtpk(xv[0], xv[1]); pkx[1] = cvtpk(xv[2], xv[3]);
        pkx[2] = cvtpk(xv[4], xv[5]); pkx[3] = cvtpk(xv[6], xv[7]);
        float yp = pipe_tile(pkx, WTB, P4, ln, Q);
        if (Q == 0) {
            float yv = yp + ybias;
            if (sg == 0) { if (tl < L0T) s0 += yv; }
            else {
                if (tl < L1T)       s1 += yv;
                else if (tl == L1T) s2 += yv;
            }
        }
    }

    s0 += __shfl_xor(s0, 1); s0 += __shfl_xor(s0, 2);
    s0 += __shfl_xor(s0, 4); s0 += __shfl_xor(s0, 8);
    s1 += __shfl_xor(s1, 1); s1 += __shfl_xor(s1, 2);
    s1 += __shfl_xor(s1, 4); s1 += __shfl_xor(s1, 8);
    s2 += __shfl_xor(s2, 1); s2 += __shfl_xor(s2, 2);
    s2 += __shfl_xor(s2, 4); s2 += __shfl_xor(s2, 8);
    if (ln == 0) { red[w * 3] = s0; red[w * 3 + 1] = s1; red[w * 3 + 2] = s2; }
    __syncthreads();
    if (tid == 0) {
        float a0 = 0.f, a1 = 0.f, a2 = 0.f;
        #pragma unroll
        for (int k = 0; k < NW; k++) {
            a0 += red[k * 3]; a1 += red[k * 3 + 1]; a2 += red[k * 3 + 2];
        }
        out[b] = a0 / (float)L0T + a1 / (float)L1T + a2;
    }
}

extern "C" void kernel_launch(void* const* d_in, const int* in_sizes, int n_in,
                              void* d_out, int out_size, void* d_ws, size_t ws_size,
                              hipStream_t stream)
{
    const float* x0   = (const float*)d_in[0];
    const float* x1   = (const float*)d_in[1];
    const float* pos0 = (const float*)d_in[2];
    const float* pos1 = (const float*)d_in[3];
    const float* xcT  = (const float*)d_in[4];
    const float* e0w1 = (const float*)d_in[5];
    const float* e0b1 = (const float*)d_in[6];
    const float* e0w2 = (const float*)d_in[7];
    const float* e0b2 = (const float*)d_in[8];
    const float* e1w1 = (const float*)d_in[9];
    const float* e1b1 = (const float*)d_in[10];
    const float* e1w2 = (const float*)d_in[11];
    const float* e1b2 = (const float*)d_in[12];
    const float* ecw1 = (const float*)d_in[13];
    const float* ecb1 = (const float*)d_in[14];
    const float* ecw2 = (const float*)d_in[15];
    const float* ecb2 = (const float*)d_in[16];
    const float* wq   = (const float*)d_in[17];
    const float* wk   = (const float*)d_in[18];
    const float* wv   = (const float*)d_in[19];
    const float* wo   = (const float*)d_in[20];
    const float* ln1g = (const float*)d_in[21];
    const float* ln1b = (const float*)d_in[22];
    const float* ln2g = (const float*)d_in[23];
    const float* ln2b = (const float*)d_in[24];
    const float* f1w1 = (const float*)d_in[25];
    const float* f1b1 = (const float*)d_in[26];
    const float* f1w2 = (const float*)d_in[27];
    const float* f1b2 = (const float*)d_in[28];
    const float* f2w1 = (const float*)d_in[29];
    const float* f2b1 = (const float*)d_in[30];
    const float* f2w2 = (const float*)d_in[31];
    const float* f2b2 = (const float*)d_in[32];
    float* out = (float*)d_out;

    const int B = in_sizes[0] / (L0T * 8);

    unsigned short* wsWb = (unsigned short*)d_ws;                  // B*1024 bf16
    float* wsEC = (float*)((char*)d_ws + (size_t)B * 1024 * 2);    // B*32 f32
    size_t offX = (size_t)B * 1024 * 2 + (size_t)B * 32 * 4;
    size_t needX = offX + (size_t)B * NTILE * 64 * 16;             // B*46*64 uvec4
    const bool lite = (ws_size >= needX);
    uvec4* wsX = lite ? (uvec4*)((char*)d_ws + offX) : (uvec4*)nullptr;

    hipLaunchKernelGGL(embed_gram_kernel, dim3(B), dim3(NTHR), 0, stream,
                       x0, x1, pos0, pos1, xcT,
                       e0w1, e0b1, e0w2, e0b2, e1w1, e1b1, e1w2, e1b2,
                       ecw1, ecb1, ecw2, ecb2, wq, wk, wv, wo,
                       wsWb, wsEC, wsX);
    if (lite) {
        hipLaunchKernelGGL(pipeline_lite_kernel, dim3(B), dim3(NTHR), 0, stream,
                           ln1g, ln1b, ln2g, ln2b,
                           f1w1, f1b1, f1w2, f1b2, f2w1, f2b1, f2w2, f2b2,
                           wsWb, wsX, out);
    } else {
        hipLaunchKernelGGL(pipeline_full_kernel, dim3(B), dim3(NTHR), 0, stream,
                           x0, x1, pos0, pos1,
                           e0w1, e0b1, e0w2, e0b2, e1w1, e1b1, e1w2, e1b2,
                           ln1g, ln1b, ln2g, ln2b,
                           f1w1, f1b1, f1w2, f1b2, f2w1, f2b1, f2w2, f2b2,
                           wsWb, wsEC, out);
    }
}